// Round 2
// baseline (1477.012 us; speedup 1.0000x reference)
//
#include <hip/hip_runtime.h>
#include <hip/hip_bf16.h>
#include <cstdint>
#include <cstddef>

typedef unsigned short u16;
using f32x4 = __attribute__((ext_vector_type(4))) float;
using s16x8 = __attribute__((ext_vector_type(8))) short;

#define NB   16
#define NH   56
#define NW   56
#define NDIM 384
#define NMED 768
#define NFIL 4
#define NRH  96
#define NWF  29
#define NPIX (NB*NH*NW)   // 50176

__device__ __forceinline__ float bf2f(u16 u){
  union { float f; unsigned int i; } w; w.i = ((unsigned int)u) << 16; return w.f;
}
__device__ __forceinline__ u16 f2bf(float f){
  union { float f; unsigned int i; } w; w.f = f;
  unsigned int i = w.i;
  return (u16)((i + 0x7fffu + ((i >> 16) & 1u)) >> 16);
}

// ---------------- small init kernels ----------------

// twiddle tables: tW[k2*56+w]=(cos,sin) fwd-W; tH[k1*56+h]=(cos,sin) H axis;
// tAB[w*29+k2]=(alpha,beta) Hermitian-folded inverse along W.
__global__ __launch_bounds__(256) void k_tables(float2* tW, float2* tH, float2* tAB){
  int i = blockIdx.x*256 + threadIdx.x;
  const float PI2 = 6.28318530717958647692f;
  if (i < NWF*56){
    int k = i / 56, w = i % 56;
    float a = PI2 * (float)((k*w) % 56) * (1.0f/56.0f);
    tW[i] = make_float2(cosf(a), sinf(a));
  } else if (i < NWF*56 + 56*56){
    int j = i - NWF*56;
    int k = j / 56, h = j % 56;
    float a = PI2 * (float)((k*h) % 56) * (1.0f/56.0f);
    tH[j] = make_float2(cosf(a), sinf(a));
  } else if (i < NWF*56 + 56*56 + 56*NWF){
    int j = i - (NWF*56 + 56*56);
    int w = j / NWF, k = j % NWF;
    float al, be;
    if (k == 0)       { al = 1.0f; be = 0.0f; }
    else if (k == 28) { al = (w & 1) ? -1.0f : 1.0f; be = 0.0f; }
    else {
      float a = PI2 * (float)((k*w) % 56) * (1.0f/56.0f);
      al = 2.0f*cosf(a); be = -2.0f*sinf(a);
    }
    tAB[j] = make_float2(al, be);
  }
}

// transpose+convert weight: w[K][N] fp32 -> wt[N][K] bf16
__global__ __launch_bounds__(256) void k_wt(const float* __restrict__ w, u16* __restrict__ wt, int K, int N){
  int i = blockIdx.x*256 + threadIdx.x;
  if (i >= K*N) return;
  int k = i / N, n = i % N;
  wt[(size_t)n*K + k] = f2bf(w[i]);
}

// ---------------- routing ----------------

__global__ __launch_bounds__(384) void k_gpart(const float* __restrict__ x, float* __restrict__ gp){
  int d = threadIdx.x, h = blockIdx.x, b = blockIdx.y;
  const float* xp = x + ((size_t)(b*NH + h)*NW)*NDIM + d;
  float s = 0.f;
  for (int w = 0; w < NW; ++w) s += xp[(size_t)w*NDIM];
  gp[(size_t)(b*NH + h)*NDIM + d] = s;
}

__global__ __launch_bounds__(384) void k_gfinal(const float* __restrict__ gp, float* __restrict__ g){
  int d = threadIdx.x, b = blockIdx.x;
  float s = 0.f;
  for (int h = 0; h < NH; ++h) s += gp[(size_t)(b*NH + h)*NDIM + d];
  g[b*NDIM + d] = s * (1.0f/3136.0f);
}

__global__ __launch_bounds__(256) void k_routing(const float* __restrict__ g,
    const float* __restrict__ w_r1, const float* __restrict__ rs, const float* __restrict__ rb,
    const float* __restrict__ w_r2, float* __restrict__ rout){
  int b = blockIdx.x, t = threadIdx.x;
  __shared__ float lg[NDIM], lh[NRH], lraw[NFIL*NMED];
  for (int i = t; i < NDIM; i += 256) lg[i] = g[b*NDIM + i];
  __syncthreads();
  if (t < NRH){
    float a = 0.f;
    for (int d = 0; d < NDIM; ++d) a = fmaf(lg[d], w_r1[d*NRH + t], a);
    float r = fmaxf(a, 0.f);
    lh[t] = rs[0]*r*r + rb[0];
  }
  __syncthreads();
  for (int o = t; o < NFIL*NMED; o += 256){
    float a = 0.f;
    for (int i = 0; i < NRH; ++i) a = fmaf(lh[i], w_r2[i*(NFIL*NMED) + o], a);
    lraw[o] = a;
  }
  __syncthreads();
  for (int c = t; c < NMED; c += 256){
    float m = lraw[c];
    for (int f = 1; f < NFIL; ++f) m = fmaxf(m, lraw[f*NMED + c]);
    float e0 = expf(lraw[0*NMED+c]-m), e1 = expf(lraw[1*NMED+c]-m),
          e2 = expf(lraw[2*NMED+c]-m), e3 = expf(lraw[3*NMED+c]-m);
    float inv = 1.0f/(e0+e1+e2+e3);
    rout[(b*NFIL+0)*NMED + c] = e0*inv;
    rout[(b*NFIL+1)*NMED + c] = e1*inv;
    rout[(b*NFIL+2)*NMED + c] = e2*inv;
    rout[(b*NFIL+3)*NMED + c] = e3*inv;
  }
}

// ---------------- bf16 MFMA GEMM: C[M,N] = A[M,K] * BT[N,K]^T ----------------
// TA=float: A is fp32, converted to bf16 during staging. TA=u16: A already bf16.
// EPI=0: StarReLU epilogue -> bf16 out. EPI=1: plain fp32 out.

template<int EPI, typename TA>
__global__ __launch_bounds__(256) void gemm_bt(const TA* __restrict__ A, const u16* __restrict__ BT,
    float* __restrict__ Cf, u16* __restrict__ Cb, int M, int N, int K,
    const float* __restrict__ scp, const float* __restrict__ bip){
  __shared__ __align__(16) u16 lA[128*40];
  __shared__ __align__(16) u16 lB[128*40];
  int t = threadIdx.x;
  int m0 = blockIdx.x*128, n0 = blockIdx.y*128;
  int lane = t & 63, wid = t >> 6;
  int wr = (wid >> 1) * 64, wc = (wid & 1) * 64;
  int lr = lane & 15, kg = lane >> 4;
  f32x4 acc[4][4] = {};

  for (int k0 = 0; k0 < K; k0 += 32){
    #pragma unroll
    for (int j = 0; j < 2; ++j){
      int q = t + 256*j;
      int row = q >> 2, seg = q & 3;
      if constexpr (sizeof(TA) == 4){
        const float* ap = (const float*)(A + (size_t)(m0+row)*K + k0 + seg*8);
        float4 f0 = *(const float4*)ap;
        float4 f1 = *(const float4*)(ap + 4);
        union { s16x8 v8; int4 i4; } u;
        u.v8[0]=(short)f2bf(f0.x); u.v8[1]=(short)f2bf(f0.y);
        u.v8[2]=(short)f2bf(f0.z); u.v8[3]=(short)f2bf(f0.w);
        u.v8[4]=(short)f2bf(f1.x); u.v8[5]=(short)f2bf(f1.y);
        u.v8[6]=(short)f2bf(f1.z); u.v8[7]=(short)f2bf(f1.w);
        *(int4*)(&lA[row*40 + seg*8]) = u.i4;
      } else {
        *(int4*)(&lA[row*40 + seg*8]) = *(const int4*)(A + (size_t)(m0+row)*K + k0 + seg*8);
      }
      *(int4*)(&lB[row*40 + seg*8]) = *(const int4*)(&BT[(size_t)(n0+row)*K + k0 + seg*8]);
    }
    __syncthreads();
    s16x8 af[4], bf[4];
    #pragma unroll
    for (int fm = 0; fm < 4; ++fm) af[fm] = *(const s16x8*)(&lA[(wr + fm*16 + lr)*40 + kg*8]);
    #pragma unroll
    for (int fn = 0; fn < 4; ++fn) bf[fn] = *(const s16x8*)(&lB[(wc + fn*16 + lr)*40 + kg*8]);
    #pragma unroll
    for (int fm = 0; fm < 4; ++fm)
      #pragma unroll
      for (int fn = 0; fn < 4; ++fn)
        acc[fm][fn] = __builtin_amdgcn_mfma_f32_16x16x32_bf16(af[fm], bf[fn], acc[fm][fn], 0, 0, 0);
    __syncthreads();
  }

  float sc = 0.f, bi = 0.f;
  if (EPI == 0){ sc = scp[0]; bi = bip[0]; }
  #pragma unroll
  for (int fm = 0; fm < 4; ++fm)
    #pragma unroll
    for (int fn = 0; fn < 4; ++fn)
      #pragma unroll
      for (int r = 0; r < 4; ++r){
        int gm = m0 + wr + fm*16 + kg*4 + r;
        int gn = n0 + wc + fn*16 + lr;
        float val = acc[fm][fn][r];
        if (EPI == 0){
          float rl = fmaxf(val, 0.f);
          val = fmaf(sc*rl, rl, bi);
          Cb[(size_t)gm*N + gn] = f2bf(val);
        } else {
          Cf[(size_t)gm*N + gn] = val;
        }
      }
}

// ---------------- depthwise 3x3 conv + BN partials ----------------

__global__ __launch_bounds__(256) void k_dwconv(const u16* __restrict__ v, const float* __restrict__ kw,
    const float* __restrict__ kb, u16* __restrict__ locraw,
    float* __restrict__ psum, float* __restrict__ psq){
  int t = threadIdx.x;
  int cc = blockIdx.x, y = blockIdx.y, b = blockIdx.z;
  int c = cc*256 + t;
  float k00 = kw[0*NMED+c], k01 = kw[1*NMED+c], k02 = kw[2*NMED+c];
  float k10 = kw[3*NMED+c], k11 = kw[4*NMED+c], k12 = kw[5*NMED+c];
  float k20 = kw[6*NMED+c], k21 = kw[7*NMED+c], k22 = kw[8*NMED+c];
  float bias = kb[c];
  bool v0 = (y-1) >= 0, v2 = (y+1) < NH;
  const u16* r0 = v + ((size_t)((b*NH + y-1)*NW))*NMED + c;
  const u16* r1 = v + ((size_t)((b*NH + y  )*NW))*NMED + c;
  const u16* r2 = v + ((size_t)((b*NH + y+1)*NW))*NMED + c;
  auto L0 = [&](int x)->float{ return v0 ? bf2f(r0[(size_t)x*NMED]) : 0.f; };
  auto L1 = [&](int x)->float{ return bf2f(r1[(size_t)x*NMED]); };
  auto L2 = [&](int x)->float{ return v2 ? bf2f(r2[(size_t)x*NMED]) : 0.f; };
  float a0 = 0.f, a1 = 0.f, a2 = 0.f;
  float b0 = L0(0), b1 = L1(0), b2 = L2(0);
  float c0 = L0(1), c1 = L1(1), c2 = L2(1);
  float sum = 0.f, sq = 0.f;
  u16* op = locraw + ((size_t)(b*NH + y)*NW)*NMED + c;
  for (int x = 0; x < NW; ++x){
    float o = bias;
    o = fmaf(a0,k00, fmaf(b0,k01, fmaf(c0,k02, o)));
    o = fmaf(a1,k10, fmaf(b1,k11, fmaf(c1,k12, o)));
    o = fmaf(a2,k20, fmaf(b2,k21, fmaf(c2,k22, o)));
    op[(size_t)x*NMED] = f2bf(o);
    sum += o; sq = fmaf(o, o, sq);
    a0 = b0; a1 = b1; a2 = b2;
    b0 = c0; b1 = c1; b2 = c2;
    if (x+2 < NW){ c0 = L0(x+2); c1 = L1(x+2); c2 = L2(x+2); }
    else { c0 = 0.f; c1 = 0.f; c2 = 0.f; }
  }
  psum[(size_t)(b*NH + y)*NMED + c] = sum;
  psq [(size_t)(b*NH + y)*NMED + c] = sq;
}

__global__ __launch_bounds__(256) void k_bnstats(const float* __restrict__ psum, const float* __restrict__ psq,
    const float* __restrict__ gamma, const float* __restrict__ beta,
    float* __restrict__ bnsc, float* __restrict__ bnsh){
  int c = blockIdx.x*256 + threadIdx.x;
  if (c >= NMED) return;
  float s = 0.f, q = 0.f;
  for (int j = 0; j < NB*NH; ++j){ s += psum[(size_t)j*NMED + c]; q += psq[(size_t)j*NMED + c]; }
  float mu  = s * (1.0f/(float)NPIX);
  float var = q * (1.0f/(float)NPIX) - mu*mu;
  float sc = gamma[c] * rsqrtf(var + 1e-5f);
  bnsc[c] = sc;
  bnsh[c] = beta[c] - mu*sc;
}

// ---------------- spectral stages (launched per batch-chunk of CH batches) ----------------

// forward rDFT along W: A1[bz][k2][h][c] = sum_w v[bz,h,w,c] * e^{-2pi i k2 w/56}
__global__ __launch_bounds__(256) void k_fftW(const u16* __restrict__ v,
    u16* __restrict__ A1r, u16* __restrict__ A1i, const float2* __restrict__ tW){
  int t = threadIdx.x;
  int cc = blockIdx.x, h = blockIdx.y, bz = blockIdx.z;
  int c = cc*256 + t;
  __shared__ u16 lV[56*256];
  const u16* vp = v + ((size_t)(bz*NH + h)*NW)*NMED + c;
  for (int w = 0; w < 56; ++w) lV[w*256 + t] = vp[(size_t)w*NMED];
  __syncthreads();
  for (int k2 = 0; k2 < NWF; ++k2){
    float sr = 0.f, si = 0.f;
    const float2* tw = tW + k2*56;
    for (int w = 0; w < 56; ++w){
      float f = bf2f(lV[w*256 + t]);
      float2 cs = tw[w];
      sr = fmaf(f,  cs.x, sr);
      si = fmaf(f, -cs.y, si);
    }
    size_t oi = ((size_t)(bz*NWF + k2)*NH + h)*NMED + c;
    A1r[oi] = f2bf(sr); A1i[oi] = f2bf(si);
  }
}

// DFT along H (e^{-i}) + dynamic-filter multiply + ortho norm, IN PLACE on A1.
__global__ __launch_bounds__(256) void k_fftH_mul(u16* __restrict__ A1r, u16* __restrict__ A1i,
    const float2* __restrict__ tH, const float* __restrict__ rout, const float* __restrict__ cw){
  int t = threadIdx.x;
  int cc = blockIdx.x, k2 = blockIdx.y, bz = blockIdx.z;
  int c = cc*256 + t;
  __shared__ u16 lre[56*256], lim[56*256];
  size_t base = ((size_t)(bz*NWF + k2)*NH)*NMED + c;
  for (int h = 0; h < 56; ++h){
    lre[h*256 + t] = A1r[base + (size_t)h*NMED];
    lim[h*256 + t] = A1i[base + (size_t)h*NMED];
  }
  __syncthreads();
  float rv0 = rout[(bz*NFIL+0)*NMED + c], rv1 = rout[(bz*NFIL+1)*NMED + c];
  float rv2 = rout[(bz*NFIL+2)*NMED + c], rv3 = rout[(bz*NFIL+3)*NMED + c];
  const float inv = 1.0f/3136.0f;
  for (int kc = 0; kc < 56; kc += 14){
    float ar[14], ai[14];
    #pragma unroll
    for (int i = 0; i < 14; ++i){ ar[i] = 0.f; ai[i] = 0.f; }
    for (int h = 0; h < 56; ++h){
      float xr = bf2f(lre[h*256 + t]), xi = bf2f(lim[h*256 + t]);
      #pragma unroll
      for (int i = 0; i < 14; ++i){
        float2 cs = tH[(kc+i)*56 + h];
        ar[i] = fmaf(xr, cs.x, fmaf( xi, cs.y, ar[i]));
        ai[i] = fmaf(xi, cs.x, fmaf(-xr, cs.y, ai[i]));
      }
    }
    #pragma unroll
    for (int i = 0; i < 14; ++i){
      int k1 = kc + i;
      const float* cwp = cw + ((size_t)(k1*NWF + k2)*NFIL)*2;
      float wr = rv0*cwp[0] + rv1*cwp[2] + rv2*cwp[4] + rv3*cwp[6];
      float wi = rv0*cwp[1] + rv1*cwp[3] + rv2*cwp[5] + rv3*cwp[7];
      float pr = (ar[i]*wr - ai[i]*wi) * inv;
      float pi = (ar[i]*wi + ai[i]*wr) * inv;
      size_t oi = base + (size_t)k1*NMED;
      A1r[oi] = f2bf(pr); A1i[oi] = f2bf(pi);
    }
  }
}

// inverse DFT along H (e^{+i}), IN PLACE on A1:
// Q[bz][k2][n1][c] = sum_k1 P[bz][k2][k1][c] e^{+2pi i k1 n1/56}
__global__ __launch_bounds__(256) void k_ifftH(u16* __restrict__ A1r, u16* __restrict__ A1i,
    const float2* __restrict__ tH){
  int t = threadIdx.x;
  int cc = blockIdx.x, k2 = blockIdx.y, bz = blockIdx.z;
  int c = cc*256 + t;
  __shared__ u16 lre[56*256], lim[56*256];
  size_t base = ((size_t)(bz*NWF + k2)*NH)*NMED + c;
  for (int k1 = 0; k1 < 56; ++k1){
    lre[k1*256 + t] = A1r[base + (size_t)k1*NMED];
    lim[k1*256 + t] = A1i[base + (size_t)k1*NMED];
  }
  __syncthreads();
  for (int nc = 0; nc < 56; nc += 14){
    float ar[14], ai[14];
    #pragma unroll
    for (int i = 0; i < 14; ++i){ ar[i] = 0.f; ai[i] = 0.f; }
    for (int k1 = 0; k1 < 56; ++k1){
      float pr = bf2f(lre[k1*256 + t]), pi = bf2f(lim[k1*256 + t]);
      #pragma unroll
      for (int i = 0; i < 14; ++i){
        float2 cs = tH[(nc+i)*56 + k1];   // cos,sin of +angle
        ar[i] = fmaf(pr, cs.x, fmaf(-pi, cs.y, ar[i]));
        ai[i] = fmaf(pr, cs.y, fmaf( pi, cs.x, ai[i]));
      }
    }
    #pragma unroll
    for (int i = 0; i < 14; ++i){
      size_t oi = base + (size_t)(nc + i)*NMED;
      A1r[oi] = f2bf(ar[i]); A1i[oi] = f2bf(ai[i]);
    }
  }
}

// inverse along W (Hermitian-folded, real) + BN-apply + StarReLU(loc) + add -> sbuf (bf16)
// Q layout: [bz][k2][n1][c]. sbuf may alias the v buffer (v dead for this chunk).
__global__ __launch_bounds__(256) void k_ifftW(const u16* __restrict__ Qr, const u16* __restrict__ Qi,
    const float2* __restrict__ tAB, const u16* __restrict__ locraw,
    const float* __restrict__ bnsc, const float* __restrict__ bnsh,
    const float* __restrict__ lsp, const float* __restrict__ lbp, u16* __restrict__ sbuf){
  int t = threadIdx.x;
  int cc = blockIdx.x, n1 = blockIdx.y, bz = blockIdx.z;
  int c = cc*256 + t;
  __shared__ u16 lqr[NWF*256], lqi[NWF*256];
  for (int k2 = 0; k2 < NWF; ++k2){
    size_t qi = ((size_t)(bz*NWF + k2)*NH + n1)*NMED + c;
    lqr[k2*256 + t] = Qr[qi];
    lqi[k2*256 + t] = Qi[qi];
  }
  __syncthreads();
  float bs = bnsc[c], bh = bnsh[c], ls = lsp[0], lb = lbp[0];
  for (int wc = 0; wc < 56; wc += 14){
    float acc[14];
    #pragma unroll
    for (int i = 0; i < 14; ++i) acc[i] = 0.f;
    for (int k2 = 0; k2 < NWF; ++k2){
      float qr = bf2f(lqr[k2*256 + t]), qi = bf2f(lqi[k2*256 + t]);
      #pragma unroll
      for (int i = 0; i < 14; ++i){
        float2 ab = tAB[(wc+i)*NWF + k2];
        acc[i] = fmaf(qr, ab.x, fmaf(qi, ab.y, acc[i]));
      }
    }
    #pragma unroll
    for (int i = 0; i < 14; ++i){
      int w = wc + i;
      size_t oi = ((size_t)(bz*NH + n1)*NW + w)*NMED + c;
      float lv = fmaf(bf2f(locraw[oi]), bs, bh);
      float rl = fmaxf(lv, 0.f);
      float loc = fmaf(ls*rl, rl, lb);
      sbuf[oi] = f2bf(acc[i] + loc);
    }
  }
}

// ---------------- host launch ----------------

extern "C" void kernel_launch(void* const* d_in, const int* in_sizes, int n_in,
                              void* d_out, int out_size, void* d_ws, size_t ws_size,
                              hipStream_t stream){
  const float* x       = (const float*)d_in[0];
  const float* w_pw1   = (const float*)d_in[1];
  const float* w_pw2   = (const float*)d_in[2];
  const float* a1s     = (const float*)d_in[3];
  const float* a1b     = (const float*)d_in[4];
  const float* w_r1    = (const float*)d_in[5];
  const float* r_s     = (const float*)d_in[6];
  const float* r_b     = (const float*)d_in[7];
  const float* w_r2    = (const float*)d_in[8];
  const float* dwk     = (const float*)d_in[9];
  const float* dwb     = (const float*)d_in[10];
  const float* bng     = (const float*)d_in[11];
  const float* bnb     = (const float*)d_in[12];
  const float* l_s     = (const float*)d_in[13];
  const float* l_b     = (const float*)d_in[14];
  const float* cw      = (const float*)d_in[15];
  float* out = (float*)d_out;

  char* ws = (char*)d_ws;
  size_t off = 0;
  auto al = [&](size_t n)->size_t{ off = (off + 255) & ~(size_t)255; size_t r = off; off += n; return r; };
  size_t o_tW  = al((size_t)NWF*56*sizeof(float2));
  size_t o_tH  = al((size_t)56*56*sizeof(float2));
  size_t o_tAB = al((size_t)56*NWF*sizeof(float2));
  size_t o_wT1 = al((size_t)NMED*NDIM*2);
  size_t o_wT2 = al((size_t)NDIM*NMED*2);
  size_t o_gp  = al((size_t)NB*NH*NDIM*4);
  size_t o_g   = al((size_t)NB*NDIM*4);
  size_t o_rt  = al((size_t)NB*NFIL*NMED*4);
  size_t o_ps  = al((size_t)NB*NH*NMED*4);
  size_t o_pq  = al((size_t)NB*NH*NMED*4);
  size_t o_bs  = al((size_t)NMED*4);
  size_t o_bh  = al((size_t)NMED*4);
  size_t o_v   = al((size_t)NPIX*NMED*2);     // v; per-batch reused as sb by k_ifftW

  // A1 (chunk of CH batches): pick largest CH in {16,8,4,2,1} that fits ws_size.
  const size_t a1_per_batch = (size_t)NWF*NH*NMED*2;   // bytes, one of r/i
  int CH = 16;
  size_t o_A1r = 0, o_A1i = 0, need = 0;
  for (;;){
    size_t o2 = off;
    auto al2 = [&](size_t n)->size_t{ o2 = (o2 + 255) & ~(size_t)255; size_t r = o2; o2 += n; return r; };
    o_A1r = al2((size_t)CH*a1_per_batch);
    o_A1i = al2((size_t)CH*a1_per_batch);
    need = o2;
    if (need <= ws_size || CH == 1) break;
    CH >>= 1;
  }
  if (need > ws_size) return;  // cannot fit even minimal layout: visible failure

  float2* tW  = (float2*)(ws + o_tW);
  float2* tH  = (float2*)(ws + o_tH);
  float2* tAB = (float2*)(ws + o_tAB);
  u16* wT1 = (u16*)(ws + o_wT1);
  u16* wT2 = (u16*)(ws + o_wT2);
  float* gp = (float*)(ws + o_gp);
  float* g  = (float*)(ws + o_g);
  float* rt = (float*)(ws + o_rt);
  float* ps = (float*)(ws + o_ps);
  float* pq = (float*)(ws + o_pq);
  float* bs = (float*)(ws + o_bs);
  float* bh = (float*)(ws + o_bh);
  u16* v   = (u16*)(ws + o_v);
  u16* A1r = (u16*)(ws + o_A1r);
  u16* A1i = (u16*)(ws + o_A1i);
  u16* lraw = (u16*)d_out;   // 50176*768*2 bytes == out_size*4 bytes exactly; dead before GEMM2 writes out

  int ntab = NWF*56 + 56*56 + 56*NWF;
  k_tables<<<(ntab+255)/256, 256, 0, stream>>>(tW, tH, tAB);
  k_wt<<<(NDIM*NMED+255)/256, 256, 0, stream>>>(w_pw1, wT1, NDIM, NMED);
  k_wt<<<(NMED*NDIM+255)/256, 256, 0, stream>>>(w_pw2, wT2, NMED, NDIM);

  k_gpart<<<dim3(NH, NB), 384, 0, stream>>>(x, gp);
  k_gfinal<<<NB, 384, 0, stream>>>(gp, g);
  k_routing<<<NB, 256, 0, stream>>>(g, w_r1, r_s, r_b, w_r2, rt);

  // v = StarReLU(x @ w_pw1)  [50176 x 768], fp32 A converted inline
  gemm_bt<0, float><<<dim3(NPIX/128, NMED/128), 256, 0, stream>>>(x, wT1, nullptr, v,
      NPIX, NMED, NDIM, a1s, a1b);

  // local branch (all batches) -> lraw lives in d_out
  k_dwconv<<<dim3(3, NH, NB), 256, 0, stream>>>(v, dwk, dwb, lraw, ps, pq);
  k_bnstats<<<3, 256, 0, stream>>>(ps, pq, bng, bnb, bs, bh);

  // spectral branch, CH batches at a time; (y+loc) written back over v in place
  for (int b0 = 0; b0 < NB; b0 += CH){
    size_t pixoff = (size_t)b0*NH*NW*NMED;
    k_fftW    <<<dim3(3, NH,  CH), 256, 0, stream>>>(v + pixoff, A1r, A1i, tW);
    k_fftH_mul<<<dim3(3, NWF, CH), 256, 0, stream>>>(A1r, A1i, tH, rt + (size_t)b0*NFIL*NMED, cw);
    k_ifftH   <<<dim3(3, NWF, CH), 256, 0, stream>>>(A1r, A1i, tH);
    k_ifftW   <<<dim3(3, NH,  CH), 256, 0, stream>>>(A1r, A1i, tAB, lraw + pixoff, bs, bh,
                                                     l_s, l_b, v + pixoff);
  }

  // out = (y + loc) @ w_pw2  [50176 x 384]
  gemm_bt<1, u16><<<dim3(NPIX/128, NDIM/128), 256, 0, stream>>>(v, wT2, out, nullptr,
      NPIX, NDIM, NMED, nullptr, nullptr);
}

// Round 3
// 1078.791 us; speedup vs baseline: 1.3691x; 1.3691x over previous
//
#include <hip/hip_runtime.h>
#include <hip/hip_bf16.h>
#include <cstdint>
#include <cstddef>

typedef unsigned short u16;
using f32x4 = __attribute__((ext_vector_type(4))) float;
using s16x8 = __attribute__((ext_vector_type(8))) short;

#define NB   16
#define NH   56
#define NW   56
#define NDIM 384
#define NMED 768
#define NFIL 4
#define NRH  96
#define NWF  29
#define NPIX (NB*NH*NW)   // 50176

__device__ __forceinline__ float bf2f(u16 u){
  union { float f; unsigned int i; } w; w.i = ((unsigned int)u) << 16; return w.f;
}
__device__ __forceinline__ u16 f2bf(float f){
  union { float f; unsigned int i; } w; w.f = f;
  unsigned int i = w.i;
  return (u16)((i + 0x7fffu + ((i >> 16) & 1u)) >> 16);
}

// ---------------- small init kernels ----------------

// twiddle tables: tW[k2*56+w]=(cos,sin) fwd-W; tH[k1*56+h]=(cos,sin) H axis;
// tAB[w*29+k2]=(alpha,beta) Hermitian-folded inverse along W.
__global__ __launch_bounds__(256) void k_tables(float2* tW, float2* tH, float2* tAB){
  int i = blockIdx.x*256 + threadIdx.x;
  const float PI2 = 6.28318530717958647692f;
  if (i < NWF*56){
    int k = i / 56, w = i % 56;
    float a = PI2 * (float)((k*w) % 56) * (1.0f/56.0f);
    tW[i] = make_float2(cosf(a), sinf(a));
  } else if (i < NWF*56 + 56*56){
    int j = i - NWF*56;
    int k = j / 56, h = j % 56;
    float a = PI2 * (float)((k*h) % 56) * (1.0f/56.0f);
    tH[j] = make_float2(cosf(a), sinf(a));
  } else if (i < NWF*56 + 56*56 + 56*NWF){
    int j = i - (NWF*56 + 56*56);
    int w = j / NWF, k = j % NWF;
    float al, be;
    if (k == 0)       { al = 1.0f; be = 0.0f; }
    else if (k == 28) { al = (w & 1) ? -1.0f : 1.0f; be = 0.0f; }
    else {
      float a = PI2 * (float)((k*w) % 56) * (1.0f/56.0f);
      al = 2.0f*cosf(a); be = -2.0f*sinf(a);
    }
    tAB[j] = make_float2(al, be);
  }
}

// transpose+convert weight: w[K][N] fp32 -> wt[N][K] bf16
__global__ __launch_bounds__(256) void k_wt(const float* __restrict__ w, u16* __restrict__ wt, int K, int N){
  int i = blockIdx.x*256 + threadIdx.x;
  if (i >= K*N) return;
  int k = i / N, n = i % N;
  wt[(size_t)n*K + k] = f2bf(w[i]);
}

// ---------------- routing ----------------

__global__ __launch_bounds__(384) void k_gpart(const float* __restrict__ x, float* __restrict__ gp){
  int d = threadIdx.x, h = blockIdx.x, b = blockIdx.y;
  const float* xp = x + ((size_t)(b*NH + h)*NW)*NDIM + d;
  float s = 0.f;
  for (int w = 0; w < NW; ++w) s += xp[(size_t)w*NDIM];
  gp[(size_t)(b*NH + h)*NDIM + d] = s;
}

__global__ __launch_bounds__(384) void k_gfinal(const float* __restrict__ gp, float* __restrict__ g){
  int d = threadIdx.x, b = blockIdx.x;
  float s = 0.f;
  for (int h = 0; h < NH; ++h) s += gp[(size_t)(b*NH + h)*NDIM + d];
  g[b*NDIM + d] = s * (1.0f/3136.0f);
}

// h[b][j] = StarReLU((g @ w_r1)[b][j])   grid: NB blocks x 128 thr
__global__ __launch_bounds__(128) void k_rmlp1(const float* __restrict__ g,
    const float* __restrict__ w_r1, const float* __restrict__ rs, const float* __restrict__ rb,
    float* __restrict__ hbuf){
  int b = blockIdx.x, t = threadIdx.x;
  __shared__ float lg[NDIM];
  for (int i = t; i < NDIM; i += 128) lg[i] = g[b*NDIM + i];
  __syncthreads();
  if (t < NRH){
    float a = 0.f;
    #pragma unroll 8
    for (int d = 0; d < NDIM; ++d) a = fmaf(lg[d], w_r1[d*NRH + t], a);
    float r = fmaxf(a, 0.f);
    hbuf[b*NRH + t] = rs[0]*r*r + rb[0];
  }
}

// rout[b][f][c] = softmax_f((h @ w_r2)[b][f*NMED+c])   grid: (NMED/256, NB)
__global__ __launch_bounds__(256) void k_rmlp2(const float* __restrict__ hbuf,
    const float* __restrict__ w_r2, float* __restrict__ rout){
  int b = blockIdx.y;
  int c = blockIdx.x*256 + threadIdx.x;
  __shared__ float lh[NRH];
  if (threadIdx.x < NRH) lh[threadIdx.x] = hbuf[b*NRH + threadIdx.x];
  __syncthreads();
  float a0 = 0.f, a1 = 0.f, a2 = 0.f, a3 = 0.f;
  #pragma unroll 4
  for (int i = 0; i < NRH; ++i){
    float hv = lh[i];
    const float* wp = w_r2 + (size_t)i*(NFIL*NMED) + c;
    a0 = fmaf(hv, wp[0*NMED], a0);
    a1 = fmaf(hv, wp[1*NMED], a1);
    a2 = fmaf(hv, wp[2*NMED], a2);
    a3 = fmaf(hv, wp[3*NMED], a3);
  }
  float m = fmaxf(fmaxf(a0, a1), fmaxf(a2, a3));
  float e0 = expf(a0-m), e1 = expf(a1-m), e2 = expf(a2-m), e3 = expf(a3-m);
  float inv = 1.0f/(e0+e1+e2+e3);
  rout[(b*NFIL+0)*NMED + c] = e0*inv;
  rout[(b*NFIL+1)*NMED + c] = e1*inv;
  rout[(b*NFIL+2)*NMED + c] = e2*inv;
  rout[(b*NFIL+3)*NMED + c] = e3*inv;
}

// ---------------- bf16 MFMA GEMM: C[M,N] = A[M,K] * BT[N,K]^T ----------------
// TA=float: A is fp32, converted to bf16 during staging. TA=u16: A already bf16.
// EPI=0: StarReLU epilogue -> bf16 out. EPI=1: plain fp32 out.

template<int EPI, typename TA>
__global__ __launch_bounds__(256) void gemm_bt(const TA* __restrict__ A, const u16* __restrict__ BT,
    float* __restrict__ Cf, u16* __restrict__ Cb, int M, int N, int K,
    const float* __restrict__ scp, const float* __restrict__ bip){
  __shared__ __align__(16) u16 lA[128*40];
  __shared__ __align__(16) u16 lB[128*40];
  int t = threadIdx.x;
  int m0 = blockIdx.x*128, n0 = blockIdx.y*128;
  int lane = t & 63, wid = t >> 6;
  int wr = (wid >> 1) * 64, wc = (wid & 1) * 64;
  int lr = lane & 15, kg = lane >> 4;
  f32x4 acc[4][4] = {};

  for (int k0 = 0; k0 < K; k0 += 32){
    #pragma unroll
    for (int j = 0; j < 2; ++j){
      int q = t + 256*j;
      int row = q >> 2, seg = q & 3;
      if constexpr (sizeof(TA) == 4){
        const float* ap = (const float*)(A + (size_t)(m0+row)*K + k0 + seg*8);
        float4 f0 = *(const float4*)ap;
        float4 f1 = *(const float4*)(ap + 4);
        union { s16x8 v8; int4 i4; } u;
        u.v8[0]=(short)f2bf(f0.x); u.v8[1]=(short)f2bf(f0.y);
        u.v8[2]=(short)f2bf(f0.z); u.v8[3]=(short)f2bf(f0.w);
        u.v8[4]=(short)f2bf(f1.x); u.v8[5]=(short)f2bf(f1.y);
        u.v8[6]=(short)f2bf(f1.z); u.v8[7]=(short)f2bf(f1.w);
        *(int4*)(&lA[row*40 + seg*8]) = u.i4;
      } else {
        *(int4*)(&lA[row*40 + seg*8]) = *(const int4*)(A + (size_t)(m0+row)*K + k0 + seg*8);
      }
      *(int4*)(&lB[row*40 + seg*8]) = *(const int4*)(&BT[(size_t)(n0+row)*K + k0 + seg*8]);
    }
    __syncthreads();
    s16x8 af[4], bf[4];
    #pragma unroll
    for (int fm = 0; fm < 4; ++fm) af[fm] = *(const s16x8*)(&lA[(wr + fm*16 + lr)*40 + kg*8]);
    #pragma unroll
    for (int fn = 0; fn < 4; ++fn) bf[fn] = *(const s16x8*)(&lB[(wc + fn*16 + lr)*40 + kg*8]);
    #pragma unroll
    for (int fm = 0; fm < 4; ++fm)
      #pragma unroll
      for (int fn = 0; fn < 4; ++fn)
        acc[fm][fn] = __builtin_amdgcn_mfma_f32_16x16x32_bf16(af[fm], bf[fn], acc[fm][fn], 0, 0, 0);
    __syncthreads();
  }

  float sc = 0.f, bi = 0.f;
  if (EPI == 0){ sc = scp[0]; bi = bip[0]; }
  #pragma unroll
  for (int fm = 0; fm < 4; ++fm)
    #pragma unroll
    for (int fn = 0; fn < 4; ++fn)
      #pragma unroll
      for (int r = 0; r < 4; ++r){
        int gm = m0 + wr + fm*16 + kg*4 + r;
        int gn = n0 + wc + fn*16 + lr;
        float val = acc[fm][fn][r];
        if (EPI == 0){
          float rl = fmaxf(val, 0.f);
          val = fmaf(sc*rl, rl, bi);
          Cb[(size_t)gm*N + gn] = f2bf(val);
        } else {
          Cf[(size_t)gm*N + gn] = val;
        }
      }
}

// ---------------- depthwise 3x3 conv + BN partials ----------------

__global__ __launch_bounds__(256) void k_dwconv(const u16* __restrict__ v, const float* __restrict__ kw,
    const float* __restrict__ kb, u16* __restrict__ locraw,
    float* __restrict__ psum, float* __restrict__ psq){
  int t = threadIdx.x;
  int cc = blockIdx.x, y = blockIdx.y, b = blockIdx.z;
  int c = cc*256 + t;
  float k00 = kw[0*NMED+c], k01 = kw[1*NMED+c], k02 = kw[2*NMED+c];
  float k10 = kw[3*NMED+c], k11 = kw[4*NMED+c], k12 = kw[5*NMED+c];
  float k20 = kw[6*NMED+c], k21 = kw[7*NMED+c], k22 = kw[8*NMED+c];
  float bias = kb[c];
  bool v0 = (y-1) >= 0, v2 = (y+1) < NH;
  const u16* r0 = v + ((size_t)((b*NH + y-1)*NW))*NMED + c;
  const u16* r1 = v + ((size_t)((b*NH + y  )*NW))*NMED + c;
  const u16* r2 = v + ((size_t)((b*NH + y+1)*NW))*NMED + c;
  auto L0 = [&](int x)->float{ return v0 ? bf2f(r0[(size_t)x*NMED]) : 0.f; };
  auto L1 = [&](int x)->float{ return bf2f(r1[(size_t)x*NMED]); };
  auto L2 = [&](int x)->float{ return v2 ? bf2f(r2[(size_t)x*NMED]) : 0.f; };
  float a0 = 0.f, a1 = 0.f, a2 = 0.f;
  float b0 = L0(0), b1 = L1(0), b2 = L2(0);
  float c0 = L0(1), c1 = L1(1), c2 = L2(1);
  float sum = 0.f, sq = 0.f;
  u16* op = locraw + ((size_t)(b*NH + y)*NW)*NMED + c;
  for (int x = 0; x < NW; ++x){
    float o = bias;
    o = fmaf(a0,k00, fmaf(b0,k01, fmaf(c0,k02, o)));
    o = fmaf(a1,k10, fmaf(b1,k11, fmaf(c1,k12, o)));
    o = fmaf(a2,k20, fmaf(b2,k21, fmaf(c2,k22, o)));
    op[(size_t)x*NMED] = f2bf(o);
    sum += o; sq = fmaf(o, o, sq);
    a0 = b0; a1 = b1; a2 = b2;
    b0 = c0; b1 = c1; b2 = c2;
    if (x+2 < NW){ c0 = L0(x+2); c1 = L1(x+2); c2 = L2(x+2); }
    else { c0 = 0.f; c1 = 0.f; c2 = 0.f; }
  }
  psum[(size_t)(b*NH + y)*NMED + c] = sum;
  psq [(size_t)(b*NH + y)*NMED + c] = sq;
}

__global__ __launch_bounds__(256) void k_bnstats(const float* __restrict__ psum, const float* __restrict__ psq,
    const float* __restrict__ gamma, const float* __restrict__ beta,
    float* __restrict__ bnsc, float* __restrict__ bnsh){
  int c = blockIdx.x*256 + threadIdx.x;
  if (c >= NMED) return;
  float s = 0.f, q = 0.f;
  for (int j = 0; j < NB*NH; ++j){ s += psum[(size_t)j*NMED + c]; q += psq[(size_t)j*NMED + c]; }
  float mu  = s * (1.0f/(float)NPIX);
  float var = q * (1.0f/(float)NPIX) - mu*mu;
  float sc = gamma[c] * rsqrtf(var + 1e-5f);
  bnsc[c] = sc;
  bnsh[c] = beta[c] - mu*sc;
}

// ---------------- spectral stages (launched per batch-chunk of CH batches) ----------------

// forward rDFT along W: A1[bz][k2][h][c] = sum_w v[bz,h,w,c] * e^{-2pi i k2 w/56}
__global__ __launch_bounds__(256) void k_fftW(const u16* __restrict__ v,
    u16* __restrict__ A1r, u16* __restrict__ A1i, const float2* __restrict__ tW){
  int t = threadIdx.x;
  int cc = blockIdx.x, h = blockIdx.y, bz = blockIdx.z;
  int c = cc*256 + t;
  __shared__ u16 lV[56*256];
  const u16* vp = v + ((size_t)(bz*NH + h)*NW)*NMED + c;
  for (int w = 0; w < 56; ++w) lV[w*256 + t] = vp[(size_t)w*NMED];
  __syncthreads();
  for (int k2 = 0; k2 < NWF; ++k2){
    float sr = 0.f, si = 0.f;
    const float2* tw = tW + k2*56;
    for (int w = 0; w < 56; ++w){
      float f = bf2f(lV[w*256 + t]);
      float2 cs = tw[w];
      sr = fmaf(f,  cs.x, sr);
      si = fmaf(f, -cs.y, si);
    }
    size_t oi = ((size_t)(bz*NWF + k2)*NH + h)*NMED + c;
    A1r[oi] = f2bf(sr); A1i[oi] = f2bf(si);
  }
}

// DFT along H (e^{-i}) + dynamic-filter multiply + ortho norm, IN PLACE on A1.
__global__ __launch_bounds__(256) void k_fftH_mul(u16* __restrict__ A1r, u16* __restrict__ A1i,
    const float2* __restrict__ tH, const float* __restrict__ rout, const float* __restrict__ cw){
  int t = threadIdx.x;
  int cc = blockIdx.x, k2 = blockIdx.y, bz = blockIdx.z;
  int c = cc*256 + t;
  __shared__ u16 lre[56*256], lim[56*256];
  size_t base = ((size_t)(bz*NWF + k2)*NH)*NMED + c;
  for (int h = 0; h < 56; ++h){
    lre[h*256 + t] = A1r[base + (size_t)h*NMED];
    lim[h*256 + t] = A1i[base + (size_t)h*NMED];
  }
  __syncthreads();
  float rv0 = rout[(bz*NFIL+0)*NMED + c], rv1 = rout[(bz*NFIL+1)*NMED + c];
  float rv2 = rout[(bz*NFIL+2)*NMED + c], rv3 = rout[(bz*NFIL+3)*NMED + c];
  const float inv = 1.0f/3136.0f;
  for (int kc = 0; kc < 56; kc += 14){
    float ar[14], ai[14];
    #pragma unroll
    for (int i = 0; i < 14; ++i){ ar[i] = 0.f; ai[i] = 0.f; }
    for (int h = 0; h < 56; ++h){
      float xr = bf2f(lre[h*256 + t]), xi = bf2f(lim[h*256 + t]);
      #pragma unroll
      for (int i = 0; i < 14; ++i){
        float2 cs = tH[(kc+i)*56 + h];
        ar[i] = fmaf(xr, cs.x, fmaf( xi, cs.y, ar[i]));
        ai[i] = fmaf(xi, cs.x, fmaf(-xr, cs.y, ai[i]));
      }
    }
    #pragma unroll
    for (int i = 0; i < 14; ++i){
      int k1 = kc + i;
      const float* cwp = cw + ((size_t)(k1*NWF + k2)*NFIL)*2;
      float wr = rv0*cwp[0] + rv1*cwp[2] + rv2*cwp[4] + rv3*cwp[6];
      float wi = rv0*cwp[1] + rv1*cwp[3] + rv2*cwp[5] + rv3*cwp[7];
      float pr = (ar[i]*wr - ai[i]*wi) * inv;
      float pi = (ar[i]*wi + ai[i]*wr) * inv;
      size_t oi = base + (size_t)k1*NMED;
      A1r[oi] = f2bf(pr); A1i[oi] = f2bf(pi);
    }
  }
}

// inverse DFT along H (e^{+i}), IN PLACE on A1:
// Q[bz][k2][n1][c] = sum_k1 P[bz][k2][k1][c] e^{+2pi i k1 n1/56}
__global__ __launch_bounds__(256) void k_ifftH(u16* __restrict__ A1r, u16* __restrict__ A1i,
    const float2* __restrict__ tH){
  int t = threadIdx.x;
  int cc = blockIdx.x, k2 = blockIdx.y, bz = blockIdx.z;
  int c = cc*256 + t;
  __shared__ u16 lre[56*256], lim[56*256];
  size_t base = ((size_t)(bz*NWF + k2)*NH)*NMED + c;
  for (int k1 = 0; k1 < 56; ++k1){
    lre[k1*256 + t] = A1r[base + (size_t)k1*NMED];
    lim[k1*256 + t] = A1i[base + (size_t)k1*NMED];
  }
  __syncthreads();
  for (int nc = 0; nc < 56; nc += 14){
    float ar[14], ai[14];
    #pragma unroll
    for (int i = 0; i < 14; ++i){ ar[i] = 0.f; ai[i] = 0.f; }
    for (int k1 = 0; k1 < 56; ++k1){
      float pr = bf2f(lre[k1*256 + t]), pi = bf2f(lim[k1*256 + t]);
      #pragma unroll
      for (int i = 0; i < 14; ++i){
        float2 cs = tH[(nc+i)*56 + k1];   // cos,sin of +angle
        ar[i] = fmaf(pr, cs.x, fmaf(-pi, cs.y, ar[i]));
        ai[i] = fmaf(pr, cs.y, fmaf( pi, cs.x, ai[i]));
      }
    }
    #pragma unroll
    for (int i = 0; i < 14; ++i){
      size_t oi = base + (size_t)(nc + i)*NMED;
      A1r[oi] = f2bf(ar[i]); A1i[oi] = f2bf(ai[i]);
    }
  }
}

// inverse along W (Hermitian-folded, real) + BN-apply + StarReLU(loc) + add -> sbuf (bf16)
// Q layout: [bz][k2][n1][c]. sbuf may alias the v buffer (v dead for this chunk).
__global__ __launch_bounds__(256) void k_ifftW(const u16* __restrict__ Qr, const u16* __restrict__ Qi,
    const float2* __restrict__ tAB, const u16* __restrict__ locraw,
    const float* __restrict__ bnsc, const float* __restrict__ bnsh,
    const float* __restrict__ lsp, const float* __restrict__ lbp, u16* __restrict__ sbuf){
  int t = threadIdx.x;
  int cc = blockIdx.x, n1 = blockIdx.y, bz = blockIdx.z;
  int c = cc*256 + t;
  __shared__ u16 lqr[NWF*256], lqi[NWF*256];
  for (int k2 = 0; k2 < NWF; ++k2){
    size_t qi = ((size_t)(bz*NWF + k2)*NH + n1)*NMED + c;
    lqr[k2*256 + t] = Qr[qi];
    lqi[k2*256 + t] = Qi[qi];
  }
  __syncthreads();
  float bs = bnsc[c], bh = bnsh[c], ls = lsp[0], lb = lbp[0];
  for (int wc = 0; wc < 56; wc += 14){
    float acc[14];
    #pragma unroll
    for (int i = 0; i < 14; ++i) acc[i] = 0.f;
    for (int k2 = 0; k2 < NWF; ++k2){
      float qr = bf2f(lqr[k2*256 + t]), qi = bf2f(lqi[k2*256 + t]);
      #pragma unroll
      for (int i = 0; i < 14; ++i){
        float2 ab = tAB[(wc+i)*NWF + k2];
        acc[i] = fmaf(qr, ab.x, fmaf(qi, ab.y, acc[i]));
      }
    }
    #pragma unroll
    for (int i = 0; i < 14; ++i){
      int w = wc + i;
      size_t oi = ((size_t)(bz*NH + n1)*NW + w)*NMED + c;
      float lv = fmaf(bf2f(locraw[oi]), bs, bh);
      float rl = fmaxf(lv, 0.f);
      float loc = fmaf(ls*rl, rl, lb);
      sbuf[oi] = f2bf(acc[i] + loc);
    }
  }
}

// ---------------- host launch ----------------

extern "C" void kernel_launch(void* const* d_in, const int* in_sizes, int n_in,
                              void* d_out, int out_size, void* d_ws, size_t ws_size,
                              hipStream_t stream){
  const float* x       = (const float*)d_in[0];
  const float* w_pw1   = (const float*)d_in[1];
  const float* w_pw2   = (const float*)d_in[2];
  const float* a1s     = (const float*)d_in[3];
  const float* a1b     = (const float*)d_in[4];
  const float* w_r1    = (const float*)d_in[5];
  const float* r_s     = (const float*)d_in[6];
  const float* r_b     = (const float*)d_in[7];
  const float* w_r2    = (const float*)d_in[8];
  const float* dwk     = (const float*)d_in[9];
  const float* dwb     = (const float*)d_in[10];
  const float* bng     = (const float*)d_in[11];
  const float* bnb     = (const float*)d_in[12];
  const float* l_s     = (const float*)d_in[13];
  const float* l_b     = (const float*)d_in[14];
  const float* cw      = (const float*)d_in[15];
  float* out = (float*)d_out;

  char* ws = (char*)d_ws;
  size_t off = 0;
  auto al = [&](size_t n)->size_t{ off = (off + 255) & ~(size_t)255; size_t r = off; off += n; return r; };
  size_t o_tW  = al((size_t)NWF*56*sizeof(float2));
  size_t o_tH  = al((size_t)56*56*sizeof(float2));
  size_t o_tAB = al((size_t)56*NWF*sizeof(float2));
  size_t o_wT1 = al((size_t)NMED*NDIM*2);
  size_t o_wT2 = al((size_t)NDIM*NMED*2);
  size_t o_gp  = al((size_t)NB*NH*NDIM*4);
  size_t o_g   = al((size_t)NB*NDIM*4);
  size_t o_h   = al((size_t)NB*NRH*4);
  size_t o_rt  = al((size_t)NB*NFIL*NMED*4);
  size_t o_ps  = al((size_t)NB*NH*NMED*4);
  size_t o_pq  = al((size_t)NB*NH*NMED*4);
  size_t o_bs  = al((size_t)NMED*4);
  size_t o_bh  = al((size_t)NMED*4);
  size_t o_v   = al((size_t)NPIX*NMED*2);     // v; per-batch reused as sb by k_ifftW

  // A1 (chunk of CH batches): pick largest CH in {16,8,4,2,1} that fits ws_size.
  const size_t a1_per_batch = (size_t)NWF*NH*NMED*2;   // bytes, one of r/i
  int CH = 16;
  size_t o_A1r = 0, o_A1i = 0, need = 0;
  for (;;){
    size_t o2 = off;
    auto al2 = [&](size_t n)->size_t{ o2 = (o2 + 255) & ~(size_t)255; size_t r = o2; o2 += n; return r; };
    o_A1r = al2((size_t)CH*a1_per_batch);
    o_A1i = al2((size_t)CH*a1_per_batch);
    need = o2;
    if (need <= ws_size || CH == 1) break;
    CH >>= 1;
  }
  if (need > ws_size) return;  // cannot fit even minimal layout: visible failure

  float2* tW  = (float2*)(ws + o_tW);
  float2* tH  = (float2*)(ws + o_tH);
  float2* tAB = (float2*)(ws + o_tAB);
  u16* wT1 = (u16*)(ws + o_wT1);
  u16* wT2 = (u16*)(ws + o_wT2);
  float* gp = (float*)(ws + o_gp);
  float* g  = (float*)(ws + o_g);
  float* hb = (float*)(ws + o_h);
  float* rt = (float*)(ws + o_rt);
  float* ps = (float*)(ws + o_ps);
  float* pq = (float*)(ws + o_pq);
  float* bs = (float*)(ws + o_bs);
  float* bh = (float*)(ws + o_bh);
  u16* v   = (u16*)(ws + o_v);
  u16* A1r = (u16*)(ws + o_A1r);
  u16* A1i = (u16*)(ws + o_A1i);
  u16* lraw = (u16*)d_out;   // 50176*768*2 bytes == out_size*4 bytes exactly; dead before GEMM2 writes out

  int ntab = NWF*56 + 56*56 + 56*NWF;
  k_tables<<<(ntab+255)/256, 256, 0, stream>>>(tW, tH, tAB);
  k_wt<<<(NDIM*NMED+255)/256, 256, 0, stream>>>(w_pw1, wT1, NDIM, NMED);
  k_wt<<<(NMED*NDIM+255)/256, 256, 0, stream>>>(w_pw2, wT2, NMED, NDIM);

  k_gpart<<<dim3(NH, NB), 384, 0, stream>>>(x, gp);
  k_gfinal<<<NB, 384, 0, stream>>>(gp, g);
  k_rmlp1<<<NB, 128, 0, stream>>>(g, w_r1, r_s, r_b, hb);
  k_rmlp2<<<dim3(NMED/256, NB), 256, 0, stream>>>(hb, w_r2, rt);

  // v = StarReLU(x @ w_pw1)  [50176 x 768], fp32 A converted inline
  gemm_bt<0, float><<<dim3(NPIX/128, NMED/128), 256, 0, stream>>>(x, wT1, nullptr, v,
      NPIX, NMED, NDIM, a1s, a1b);

  // local branch (all batches) -> lraw lives in d_out
  k_dwconv<<<dim3(3, NH, NB), 256, 0, stream>>>(v, dwk, dwb, lraw, ps, pq);
  k_bnstats<<<3, 256, 0, stream>>>(ps, pq, bng, bnb, bs, bh);

  // spectral branch, CH batches at a time; (y+loc) written back over v in place
  for (int b0 = 0; b0 < NB; b0 += CH){
    size_t pixoff = (size_t)b0*NH*NW*NMED;
    k_fftW    <<<dim3(3, NH,  CH), 256, 0, stream>>>(v + pixoff, A1r, A1i, tW);
    k_fftH_mul<<<dim3(3, NWF, CH), 256, 0, stream>>>(A1r, A1i, tH, rt + (size_t)b0*NFIL*NMED, cw);
    k_ifftH   <<<dim3(3, NWF, CH), 256, 0, stream>>>(A1r, A1i, tH);
    k_ifftW   <<<dim3(3, NH,  CH), 256, 0, stream>>>(A1r, A1i, tAB, lraw + pixoff, bs, bh,
                                                     l_s, l_b, v + pixoff);
  }

  // out = (y + loc) @ w_pw2  [50176 x 384]
  gemm_bt<1, u16><<<dim3(NPIX/128, NDIM/128), 256, 0, stream>>>(v, wT2, out, nullptr,
      NPIX, NDIM, NMED, nullptr, nullptr);
}

// Round 4
// 970.513 us; speedup vs baseline: 1.5219x; 1.1116x over previous
//
#include <hip/hip_runtime.h>
#include <hip/hip_bf16.h>
#include <cstdint>
#include <cstddef>

typedef unsigned short u16;
typedef unsigned int u32;
using f32x4 = __attribute__((ext_vector_type(4))) float;
using s16x8 = __attribute__((ext_vector_type(8))) short;

#define NB   16
#define NH   56
#define NW   56
#define NDIM 384
#define NMED 768
#define NFIL 4
#define NRH  96
#define NWF  29
#define NPIX (NB*NH*NW)   // 50176

__device__ __forceinline__ float bf2f(u16 u){
  union { float f; u32 i; } w; w.i = ((u32)u) << 16; return w.f;
}
__device__ __forceinline__ u16 f2bf(float f){
  union { float f; u32 i; } w; w.f = f;
  u32 i = w.i;
  return (u16)((i + 0x7fffu + ((i >> 16) & 1u)) >> 16);
}
__device__ __forceinline__ u32 packbf(float r, float i){
  return (u32)f2bf(r) | ((u32)f2bf(i) << 16);
}
__device__ __forceinline__ float unpk_lo(u32 u){
  union { float f; u32 i; } w; w.i = u << 16; return w.f;
}
__device__ __forceinline__ float unpk_hi(u32 u){
  union { float f; u32 i; } w; w.i = u & 0xffff0000u; return w.f;
}

// ---------------- small init kernels ----------------

// twiddle tables: tW[k2*56+w]=(cos,sin) fwd-W; tH[k1*56+h]=(cos,sin) H axis;
// tAB[w*29+k2]=(alpha,beta) Hermitian-folded inverse along W.
__global__ __launch_bounds__(256) void k_tables(float2* tW, float2* tH, float2* tAB){
  int i = blockIdx.x*256 + threadIdx.x;
  const float PI2 = 6.28318530717958647692f;
  if (i < NWF*56){
    int k = i / 56, w = i % 56;
    float a = PI2 * (float)((k*w) % 56) * (1.0f/56.0f);
    tW[i] = make_float2(cosf(a), sinf(a));
  } else if (i < NWF*56 + 56*56){
    int j = i - NWF*56;
    int k = j / 56, h = j % 56;
    float a = PI2 * (float)((k*h) % 56) * (1.0f/56.0f);
    tH[j] = make_float2(cosf(a), sinf(a));
  } else if (i < NWF*56 + 56*56 + 56*NWF){
    int j = i - (NWF*56 + 56*56);
    int w = j / NWF, k = j % NWF;
    float al, be;
    if (k == 0)       { al = 1.0f; be = 0.0f; }
    else if (k == 28) { al = (w & 1) ? -1.0f : 1.0f; be = 0.0f; }
    else {
      float a = PI2 * (float)((k*w) % 56) * (1.0f/56.0f);
      al = 2.0f*cosf(a); be = -2.0f*sinf(a);
    }
    tAB[j] = make_float2(al, be);
  }
}

// transpose+convert weight: w[K][N] fp32 -> wt[N][K] bf16
__global__ __launch_bounds__(256) void k_wt(const float* __restrict__ w, u16* __restrict__ wt, int K, int N){
  int i = blockIdx.x*256 + threadIdx.x;
  if (i >= K*N) return;
  int k = i / N, n = i % N;
  wt[(size_t)n*K + k] = f2bf(w[i]);
}

// ---------------- routing ----------------

__global__ __launch_bounds__(384) void k_gpart(const float* __restrict__ x, float* __restrict__ gp){
  int d = threadIdx.x, h = blockIdx.x, b = blockIdx.y;
  const float* xp = x + ((size_t)(b*NH + h)*NW)*NDIM + d;
  float s = 0.f;
  for (int w = 0; w < NW; ++w) s += xp[(size_t)w*NDIM];
  gp[(size_t)(b*NH + h)*NDIM + d] = s;
}

__global__ __launch_bounds__(384) void k_gfinal(const float* __restrict__ gp, float* __restrict__ g){
  int d = threadIdx.x, b = blockIdx.x;
  float s = 0.f;
  for (int h = 0; h < NH; ++h) s += gp[(size_t)(b*NH + h)*NDIM + d];
  g[b*NDIM + d] = s * (1.0f/3136.0f);
}

// h[b][j] = StarReLU((g @ w_r1)[b][j])   grid: NB blocks x 128 thr
__global__ __launch_bounds__(128) void k_rmlp1(const float* __restrict__ g,
    const float* __restrict__ w_r1, const float* __restrict__ rs, const float* __restrict__ rb,
    float* __restrict__ hbuf){
  int b = blockIdx.x, t = threadIdx.x;
  __shared__ float lg[NDIM];
  for (int i = t; i < NDIM; i += 128) lg[i] = g[b*NDIM + i];
  __syncthreads();
  if (t < NRH){
    float a = 0.f;
    #pragma unroll 8
    for (int d = 0; d < NDIM; ++d) a = fmaf(lg[d], w_r1[d*NRH + t], a);
    float r = fmaxf(a, 0.f);
    hbuf[b*NRH + t] = rs[0]*r*r + rb[0];
  }
}

// rout[b][f][c] = softmax_f((h @ w_r2)[b][f*NMED+c])   grid: (NMED/256, NB)
__global__ __launch_bounds__(256) void k_rmlp2(const float* __restrict__ hbuf,
    const float* __restrict__ w_r2, float* __restrict__ rout){
  int b = blockIdx.y;
  int c = blockIdx.x*256 + threadIdx.x;
  __shared__ float lh[NRH];
  if (threadIdx.x < NRH) lh[threadIdx.x] = hbuf[b*NRH + threadIdx.x];
  __syncthreads();
  float a0 = 0.f, a1 = 0.f, a2 = 0.f, a3 = 0.f;
  #pragma unroll 4
  for (int i = 0; i < NRH; ++i){
    float hv = lh[i];
    const float* wp = w_r2 + (size_t)i*(NFIL*NMED) + c;
    a0 = fmaf(hv, wp[0*NMED], a0);
    a1 = fmaf(hv, wp[1*NMED], a1);
    a2 = fmaf(hv, wp[2*NMED], a2);
    a3 = fmaf(hv, wp[3*NMED], a3);
  }
  float m = fmaxf(fmaxf(a0, a1), fmaxf(a2, a3));
  float e0 = expf(a0-m), e1 = expf(a1-m), e2 = expf(a2-m), e3 = expf(a3-m);
  float inv = 1.0f/(e0+e1+e2+e3);
  rout[(b*NFIL+0)*NMED + c] = e0*inv;
  rout[(b*NFIL+1)*NMED + c] = e1*inv;
  rout[(b*NFIL+2)*NMED + c] = e2*inv;
  rout[(b*NFIL+3)*NMED + c] = e3*inv;
}

// ---------------- bf16 MFMA GEMM: C[M,N] = A[M,K] * BT[N,K]^T ----------------
// TA=float: A is fp32, converted to bf16 during staging. TA=u16: A already bf16.
// EPI=0: StarReLU epilogue -> bf16 out. EPI=1: plain fp32 out.

template<int EPI, typename TA>
__global__ __launch_bounds__(256) void gemm_bt(const TA* __restrict__ A, const u16* __restrict__ BT,
    float* __restrict__ Cf, u16* __restrict__ Cb, int M, int N, int K,
    const float* __restrict__ scp, const float* __restrict__ bip){
  __shared__ __align__(16) u16 lA[128*40];
  __shared__ __align__(16) u16 lB[128*40];
  int t = threadIdx.x;
  int m0 = blockIdx.x*128, n0 = blockIdx.y*128;
  int lane = t & 63, wid = t >> 6;
  int wr = (wid >> 1) * 64, wc = (wid & 1) * 64;
  int lr = lane & 15, kg = lane >> 4;
  f32x4 acc[4][4] = {};

  for (int k0 = 0; k0 < K; k0 += 32){
    #pragma unroll
    for (int j = 0; j < 2; ++j){
      int q = t + 256*j;
      int row = q >> 2, seg = q & 3;
      if constexpr (sizeof(TA) == 4){
        const float* ap = (const float*)(A + (size_t)(m0+row)*K + k0 + seg*8);
        float4 f0 = *(const float4*)ap;
        float4 f1 = *(const float4*)(ap + 4);
        union { s16x8 v8; int4 i4; } u;
        u.v8[0]=(short)f2bf(f0.x); u.v8[1]=(short)f2bf(f0.y);
        u.v8[2]=(short)f2bf(f0.z); u.v8[3]=(short)f2bf(f0.w);
        u.v8[4]=(short)f2bf(f1.x); u.v8[5]=(short)f2bf(f1.y);
        u.v8[6]=(short)f2bf(f1.z); u.v8[7]=(short)f2bf(f1.w);
        *(int4*)(&lA[row*40 + seg*8]) = u.i4;
      } else {
        *(int4*)(&lA[row*40 + seg*8]) = *(const int4*)(A + (size_t)(m0+row)*K + k0 + seg*8);
      }
      *(int4*)(&lB[row*40 + seg*8]) = *(const int4*)(&BT[(size_t)(n0+row)*K + k0 + seg*8]);
    }
    __syncthreads();
    s16x8 af[4], bf[4];
    #pragma unroll
    for (int fm = 0; fm < 4; ++fm) af[fm] = *(const s16x8*)(&lA[(wr + fm*16 + lr)*40 + kg*8]);
    #pragma unroll
    for (int fn = 0; fn < 4; ++fn) bf[fn] = *(const s16x8*)(&lB[(wc + fn*16 + lr)*40 + kg*8]);
    #pragma unroll
    for (int fm = 0; fm < 4; ++fm)
      #pragma unroll
      for (int fn = 0; fn < 4; ++fn)
        acc[fm][fn] = __builtin_amdgcn_mfma_f32_16x16x32_bf16(af[fm], bf[fn], acc[fm][fn], 0, 0, 0);
    __syncthreads();
  }

  float sc = 0.f, bi = 0.f;
  if (EPI == 0){ sc = scp[0]; bi = bip[0]; }
  #pragma unroll
  for (int fm = 0; fm < 4; ++fm)
    #pragma unroll
    for (int fn = 0; fn < 4; ++fn)
      #pragma unroll
      for (int r = 0; r < 4; ++r){
        int gm = m0 + wr + fm*16 + kg*4 + r;
        int gn = n0 + wc + fn*16 + lr;
        float val = acc[fm][fn][r];
        if (EPI == 0){
          float rl = fmaxf(val, 0.f);
          val = fmaf(sc*rl, rl, bi);
          Cb[(size_t)gm*N + gn] = f2bf(val);
        } else {
          Cf[(size_t)gm*N + gn] = val;
        }
      }
}

// ---------------- depthwise 3x3 conv + BN partials ----------------

__global__ __launch_bounds__(256) void k_dwconv(const u16* __restrict__ v, const float* __restrict__ kw,
    const float* __restrict__ kb, u16* __restrict__ locraw,
    float* __restrict__ psum, float* __restrict__ psq){
  int t = threadIdx.x;
  int cc = blockIdx.x, y = blockIdx.y, b = blockIdx.z;
  int c = cc*256 + t;
  float k00 = kw[0*NMED+c], k01 = kw[1*NMED+c], k02 = kw[2*NMED+c];
  float k10 = kw[3*NMED+c], k11 = kw[4*NMED+c], k12 = kw[5*NMED+c];
  float k20 = kw[6*NMED+c], k21 = kw[7*NMED+c], k22 = kw[8*NMED+c];
  float bias = kb[c];
  bool v0 = (y-1) >= 0, v2 = (y+1) < NH;
  const u16* r0 = v + ((size_t)((b*NH + y-1)*NW))*NMED + c;
  const u16* r1 = v + ((size_t)((b*NH + y  )*NW))*NMED + c;
  const u16* r2 = v + ((size_t)((b*NH + y+1)*NW))*NMED + c;
  auto L0 = [&](int x)->float{ return v0 ? bf2f(r0[(size_t)x*NMED]) : 0.f; };
  auto L1 = [&](int x)->float{ return bf2f(r1[(size_t)x*NMED]); };
  auto L2 = [&](int x)->float{ return v2 ? bf2f(r2[(size_t)x*NMED]) : 0.f; };
  float a0 = 0.f, a1 = 0.f, a2 = 0.f;
  float b0 = L0(0), b1 = L1(0), b2 = L2(0);
  float c0 = L0(1), c1 = L1(1), c2 = L2(1);
  float sum = 0.f, sq = 0.f;
  u16* op = locraw + ((size_t)(b*NH + y)*NW)*NMED + c;
  for (int x = 0; x < NW; ++x){
    float o = bias;
    o = fmaf(a0,k00, fmaf(b0,k01, fmaf(c0,k02, o)));
    o = fmaf(a1,k10, fmaf(b1,k11, fmaf(c1,k12, o)));
    o = fmaf(a2,k20, fmaf(b2,k21, fmaf(c2,k22, o)));
    op[(size_t)x*NMED] = f2bf(o);
    sum += o; sq = fmaf(o, o, sq);
    a0 = b0; a1 = b1; a2 = b2;
    b0 = c0; b1 = c1; b2 = c2;
    if (x+2 < NW){ c0 = L0(x+2); c1 = L1(x+2); c2 = L2(x+2); }
    else { c0 = 0.f; c1 = 0.f; c2 = 0.f; }
  }
  psum[(size_t)(b*NH + y)*NMED + c] = sum;
  psq [(size_t)(b*NH + y)*NMED + c] = sq;
}

__global__ __launch_bounds__(256) void k_bnstats(const float* __restrict__ psum, const float* __restrict__ psq,
    const float* __restrict__ gamma, const float* __restrict__ beta,
    float* __restrict__ bnsc, float* __restrict__ bnsh){
  int c = blockIdx.x*256 + threadIdx.x;
  if (c >= NMED) return;
  float s = 0.f, q = 0.f;
  for (int j = 0; j < NB*NH; ++j){ s += psum[(size_t)j*NMED + c]; q += psq[(size_t)j*NMED + c]; }
  float mu  = s * (1.0f/(float)NPIX);
  float var = q * (1.0f/(float)NPIX) - mu*mu;
  float sc = gamma[c] * rsqrtf(var + 1e-5f);
  bnsc[c] = sc;
  bnsh[c] = beta[c] - mu*sc;
}

// ---------------- spectral stages ----------------
// A1p packs (re,im) bf16 into one u32 per element: lo16=re, hi16=im.

// forward rDFT along W: A1p[bz][k2][h][c] = sum_w v[bz,h,w,c] * e^{-2pi i k2 w/56}
__global__ __launch_bounds__(256) void k_fftW(const u16* __restrict__ v,
    u32* __restrict__ A1p, const float2* __restrict__ tW){
  int t = threadIdx.x;
  int cc = blockIdx.x, h = blockIdx.y, bz = blockIdx.z;
  int c = cc*256 + t;
  __shared__ u16 lV[56*256];          // 28672 B
  __shared__ float2 tWs[NWF*56];      // 12992 B
  const u16* vp = v + ((size_t)(bz*NH + h)*NW)*NMED + c;
  for (int w = 0; w < 56; ++w) lV[w*256 + t] = vp[(size_t)w*NMED];
  for (int j = t; j < NWF*56; j += 256) tWs[j] = tW[j];
  __syncthreads();
  for (int k2 = 0; k2 < NWF; ++k2){
    float sr = 0.f, si = 0.f;
    const float2* tw = tWs + k2*56;
    for (int w = 0; w < 56; ++w){
      float f = bf2f(lV[w*256 + t]);
      float2 cs = tw[w];                 // LDS broadcast (uniform addr)
      sr = fmaf(f,  cs.x, sr);
      si = fmaf(f, -cs.y, si);
    }
    size_t oi = ((size_t)(bz*NWF + k2)*NH + h)*NMED + c;
    A1p[oi] = packbf(sr, si);
  }
}

// DFT along H (e^{-i}) + dynamic-filter multiply + ortho norm, IN PLACE on A1p.
__global__ __launch_bounds__(256) void k_fftH_mul(u32* __restrict__ A1p,
    const float2* __restrict__ tH, const float* __restrict__ rout, const float* __restrict__ cw){
  int t = threadIdx.x;
  int cc = blockIdx.x, k2 = blockIdx.y, bz = blockIdx.z;
  int c = cc*256 + t;
  __shared__ u32 lX[56*256];          // 57344 B
  __shared__ float2 tHs[14*56];       // 6272 B
  __shared__ float cws[56*8];         // 1792 B   -> total 65408 B
  size_t base = ((size_t)(bz*NWF + k2)*NH)*NMED + c;
  for (int h = 0; h < 56; ++h) lX[h*256 + t] = A1p[base + (size_t)h*NMED];
  for (int j = t; j < 56*8; j += 256){
    int k1 = j >> 3, f2i = j & 7;
    cws[j] = cw[((size_t)(k1*NWF + k2))*8 + f2i];
  }
  float rv0 = rout[(bz*NFIL+0)*NMED + c], rv1 = rout[(bz*NFIL+1)*NMED + c];
  float rv2 = rout[(bz*NFIL+2)*NMED + c], rv3 = rout[(bz*NFIL+3)*NMED + c];
  const float inv = 1.0f/3136.0f;
  __syncthreads();
  for (int kc = 0; kc < 56; kc += 14){
    // stage tH slice for k1 in [kc, kc+14)
    for (int j = t; j < 14*56; j += 256) tHs[j] = tH[kc*56 + j];
    __syncthreads();
    float ar[14], ai[14];
    #pragma unroll
    for (int i = 0; i < 14; ++i){ ar[i] = 0.f; ai[i] = 0.f; }
    for (int h = 0; h < 56; ++h){
      u32 u = lX[h*256 + t];
      float xr = unpk_lo(u), xi = unpk_hi(u);
      #pragma unroll
      for (int i = 0; i < 14; ++i){
        float2 cs = tHs[i*56 + h];      // LDS broadcast
        ar[i] = fmaf(xr, cs.x, fmaf( xi, cs.y, ar[i]));
        ai[i] = fmaf(xi, cs.x, fmaf(-xr, cs.y, ai[i]));
      }
    }
    #pragma unroll
    for (int i = 0; i < 14; ++i){
      int k1 = kc + i;
      const float* cwp = cws + k1*8;
      float wr = rv0*cwp[0] + rv1*cwp[2] + rv2*cwp[4] + rv3*cwp[6];
      float wi = rv0*cwp[1] + rv1*cwp[3] + rv2*cwp[5] + rv3*cwp[7];
      float pr = (ar[i]*wr - ai[i]*wi) * inv;
      float pi = (ar[i]*wi + ai[i]*wr) * inv;
      A1p[base + (size_t)k1*NMED] = packbf(pr, pi);
    }
    __syncthreads();   // protect tHs before next pass restage
  }
}

// inverse DFT along H (e^{+i}), IN PLACE on A1p:
// Q[bz][k2][n1][c] = sum_k1 P[bz][k2][k1][c] e^{+2pi i k1 n1/56}
__global__ __launch_bounds__(256) void k_ifftH(u32* __restrict__ A1p, const float2* __restrict__ tH){
  int t = threadIdx.x;
  int cc = blockIdx.x, k2 = blockIdx.y, bz = blockIdx.z;
  int c = cc*256 + t;
  __shared__ u32 lX[56*256];          // 57344 B
  __shared__ float2 tHs[14*56];       // 6272 B  -> 63616 B
  size_t base = ((size_t)(bz*NWF + k2)*NH)*NMED + c;
  for (int k1 = 0; k1 < 56; ++k1) lX[k1*256 + t] = A1p[base + (size_t)k1*NMED];
  __syncthreads();
  for (int nc = 0; nc < 56; nc += 14){
    for (int j = t; j < 14*56; j += 256) tHs[j] = tH[nc*56 + j];
    __syncthreads();
    float ar[14], ai[14];
    #pragma unroll
    for (int i = 0; i < 14; ++i){ ar[i] = 0.f; ai[i] = 0.f; }
    for (int k1 = 0; k1 < 56; ++k1){
      u32 u = lX[k1*256 + t];
      float pr = unpk_lo(u), pi = unpk_hi(u);
      #pragma unroll
      for (int i = 0; i < 14; ++i){
        float2 cs = tHs[i*56 + k1];     // cos,sin of +angle; LDS broadcast
        ar[i] = fmaf(pr, cs.x, fmaf(-pi, cs.y, ar[i]));
        ai[i] = fmaf(pr, cs.y, fmaf( pi, cs.x, ai[i]));
      }
    }
    #pragma unroll
    for (int i = 0; i < 14; ++i){
      A1p[base + (size_t)(nc + i)*NMED] = packbf(ar[i], ai[i]);
    }
    __syncthreads();
  }
}

// inverse along W (Hermitian-folded, real) + BN-apply + StarReLU(loc) + add -> sbuf (bf16)
// Q layout: [bz][k2][n1][c] packed. sbuf may alias the v buffer (v dead for this chunk).
__global__ __launch_bounds__(256) void k_ifftW(const u32* __restrict__ Qp,
    const float2* __restrict__ tAB, const u16* __restrict__ locraw,
    const float* __restrict__ bnsc, const float* __restrict__ bnsh,
    const float* __restrict__ lsp, const float* __restrict__ lbp, u16* __restrict__ sbuf){
  int t = threadIdx.x;
  int cc = blockIdx.x, n1 = blockIdx.y, bz = blockIdx.z;
  int c = cc*256 + t;
  __shared__ u32 lq[NWF*256];         // 29696 B
  __shared__ float2 tABs[56*NWF];     // 12992 B -> 42688 B
  for (int k2 = 0; k2 < NWF; ++k2){
    size_t qi = ((size_t)(bz*NWF + k2)*NH + n1)*NMED + c;
    lq[k2*256 + t] = Qp[qi];
  }
  for (int j = t; j < 56*NWF; j += 256) tABs[j] = tAB[j];
  __syncthreads();
  float bs = bnsc[c], bh = bnsh[c], ls = lsp[0], lb = lbp[0];
  for (int wc = 0; wc < 56; wc += 14){
    float acc[14];
    #pragma unroll
    for (int i = 0; i < 14; ++i) acc[i] = 0.f;
    for (int k2 = 0; k2 < NWF; ++k2){
      u32 u = lq[k2*256 + t];
      float qr = unpk_lo(u), qi = unpk_hi(u);
      #pragma unroll
      for (int i = 0; i < 14; ++i){
        float2 ab = tABs[(wc+i)*NWF + k2];  // LDS broadcast
        acc[i] = fmaf(qr, ab.x, fmaf(qi, ab.y, acc[i]));
      }
    }
    #pragma unroll
    for (int i = 0; i < 14; ++i){
      int w = wc + i;
      size_t oi = ((size_t)(bz*NH + n1)*NW + w)*NMED + c;
      float lv = fmaf(bf2f(locraw[oi]), bs, bh);
      float rl = fmaxf(lv, 0.f);
      float loc = fmaf(ls*rl, rl, lb);
      sbuf[oi] = f2bf(acc[i] + loc);
    }
  }
}

// ---------------- host launch ----------------

extern "C" void kernel_launch(void* const* d_in, const int* in_sizes, int n_in,
                              void* d_out, int out_size, void* d_ws, size_t ws_size,
                              hipStream_t stream){
  const float* x       = (const float*)d_in[0];
  const float* w_pw1   = (const float*)d_in[1];
  const float* w_pw2   = (const float*)d_in[2];
  const float* a1s     = (const float*)d_in[3];
  const float* a1b     = (const float*)d_in[4];
  const float* w_r1    = (const float*)d_in[5];
  const float* r_s     = (const float*)d_in[6];
  const float* r_b     = (const float*)d_in[7];
  const float* w_r2    = (const float*)d_in[8];
  const float* dwk     = (const float*)d_in[9];
  const float* dwb     = (const float*)d_in[10];
  const float* bng     = (const float*)d_in[11];
  const float* bnb     = (const float*)d_in[12];
  const float* l_s     = (const float*)d_in[13];
  const float* l_b     = (const float*)d_in[14];
  const float* cw      = (const float*)d_in[15];
  float* out = (float*)d_out;

  char* ws = (char*)d_ws;
  size_t off = 0;
  auto al = [&](size_t n)->size_t{ off = (off + 255) & ~(size_t)255; size_t r = off; off += n; return r; };
  size_t o_tW  = al((size_t)NWF*56*sizeof(float2));
  size_t o_tH  = al((size_t)56*56*sizeof(float2));
  size_t o_tAB = al((size_t)56*NWF*sizeof(float2));
  size_t o_wT1 = al((size_t)NMED*NDIM*2);
  size_t o_wT2 = al((size_t)NDIM*NMED*2);
  size_t o_gp  = al((size_t)NB*NH*NDIM*4);
  size_t o_g   = al((size_t)NB*NDIM*4);
  size_t o_h   = al((size_t)NB*NRH*4);
  size_t o_rt  = al((size_t)NB*NFIL*NMED*4);
  size_t o_ps  = al((size_t)NB*NH*NMED*4);
  size_t o_pq  = al((size_t)NB*NH*NMED*4);
  size_t o_bs  = al((size_t)NMED*4);
  size_t o_bh  = al((size_t)NMED*4);
  size_t o_v   = al((size_t)NPIX*NMED*2);     // v; per-batch reused as sb by k_ifftW

  // A1p (chunk of CH batches): pick largest CH in {16,8,4,2,1} that fits ws_size.
  const size_t a1_per_batch = (size_t)NWF*NH*NMED*4;   // bytes, packed (re,im)
  int CH = 16;
  size_t o_A1 = 0, need = 0;
  for (;;){
    size_t o2 = off;
    auto al2 = [&](size_t n)->size_t{ o2 = (o2 + 255) & ~(size_t)255; size_t r = o2; o2 += n; return r; };
    o_A1 = al2((size_t)CH*a1_per_batch);
    need = o2;
    if (need <= ws_size || CH == 1) break;
    CH >>= 1;
  }
  if (need > ws_size) return;  // cannot fit even minimal layout: visible failure

  float2* tW  = (float2*)(ws + o_tW);
  float2* tH  = (float2*)(ws + o_tH);
  float2* tAB = (float2*)(ws + o_tAB);
  u16* wT1 = (u16*)(ws + o_wT1);
  u16* wT2 = (u16*)(ws + o_wT2);
  float* gp = (float*)(ws + o_gp);
  float* g  = (float*)(ws + o_g);
  float* hb = (float*)(ws + o_h);
  float* rt = (float*)(ws + o_rt);
  float* ps = (float*)(ws + o_ps);
  float* pq = (float*)(ws + o_pq);
  float* bs = (float*)(ws + o_bs);
  float* bh = (float*)(ws + o_bh);
  u16* v   = (u16*)(ws + o_v);
  u32* A1p = (u32*)(ws + o_A1);
  u16* lraw = (u16*)d_out;   // 50176*768*2 bytes == out_size*4 bytes exactly; dead before GEMM2 writes out

  int ntab = NWF*56 + 56*56 + 56*NWF;
  k_tables<<<(ntab+255)/256, 256, 0, stream>>>(tW, tH, tAB);
  k_wt<<<(NDIM*NMED+255)/256, 256, 0, stream>>>(w_pw1, wT1, NDIM, NMED);
  k_wt<<<(NMED*NDIM+255)/256, 256, 0, stream>>>(w_pw2, wT2, NMED, NDIM);

  k_gpart<<<dim3(NH, NB), 384, 0, stream>>>(x, gp);
  k_gfinal<<<NB, 384, 0, stream>>>(gp, g);
  k_rmlp1<<<NB, 128, 0, stream>>>(g, w_r1, r_s, r_b, hb);
  k_rmlp2<<<dim3(NMED/256, NB), 256, 0, stream>>>(hb, w_r2, rt);

  // v = StarReLU(x @ w_pw1)  [50176 x 768], fp32 A converted inline
  gemm_bt<0, float><<<dim3(NPIX/128, NMED/128), 256, 0, stream>>>(x, wT1, nullptr, v,
      NPIX, NMED, NDIM, a1s, a1b);

  // local branch (all batches) -> lraw lives in d_out
  k_dwconv<<<dim3(3, NH, NB), 256, 0, stream>>>(v, dwk, dwb, lraw, ps, pq);
  k_bnstats<<<3, 256, 0, stream>>>(ps, pq, bng, bnb, bs, bh);

  // spectral branch, CH batches at a time; (y+loc) written back over v in place
  for (int b0 = 0; b0 < NB; b0 += CH){
    size_t pixoff = (size_t)b0*NH*NW*NMED;
    k_fftW    <<<dim3(3, NH,  CH), 256, 0, stream>>>(v + pixoff, A1p, tW);
    k_fftH_mul<<<dim3(3, NWF, CH), 256, 0, stream>>>(A1p, tH, rt + (size_t)b0*NFIL*NMED, cw);
    k_ifftH   <<<dim3(3, NWF, CH), 256, 0, stream>>>(A1p, tH);
    k_ifftW   <<<dim3(3, NH,  CH), 256, 0, stream>>>(A1p, tAB, lraw + pixoff, bs, bh,
                                                     l_s, l_b, v + pixoff);
  }

  // out = (y + loc) @ w_pw2  [50176 x 384]
  gemm_bt<1, u16><<<dim3(NPIX/128, NDIM/128), 256, 0, stream>>>(v, wT2, out, nullptr,
      NPIX, NDIM, NMED, nullptr, nullptr);
}

// Round 5
// 715.906 us; speedup vs baseline: 2.0631x; 1.3556x over previous
//
#include <hip/hip_runtime.h>
#include <hip/hip_bf16.h>
#include <cstdint>
#include <cstddef>

typedef unsigned short u16;
typedef unsigned int u32;
using f32x4 = __attribute__((ext_vector_type(4))) float;
using s16x8 = __attribute__((ext_vector_type(8))) short;

#define NB   16
#define NH   56
#define NW   56
#define NDIM 384
#define NMED 768
#define NFIL 4
#define NRH  96
#define NWF  29
#define NPIX (NB*NH*NW)   // 50176

__device__ __forceinline__ float bf2f(u16 u){
  union { float f; u32 i; } w; w.i = ((u32)u) << 16; return w.f;
}
__device__ __forceinline__ u16 f2bf(float f){
  union { float f; u32 i; } w; w.f = f;
  u32 i = w.i;
  return (u16)((i + 0x7fffu + ((i >> 16) & 1u)) >> 16);
}
__device__ __forceinline__ u32 packbf(float r, float i){
  return (u32)f2bf(r) | ((u32)f2bf(i) << 16);
}
__device__ __forceinline__ float unpk_lo(u32 u){
  union { float f; u32 i; } w; w.i = u << 16; return w.f;
}
__device__ __forceinline__ float unpk_hi(u32 u){
  union { float f; u32 i; } w; w.i = u & 0xffff0000u; return w.f;
}
// swizzled LDS index for [row][col64] bf16 tiles (breaks 128B-stride bank conflicts)
__device__ __forceinline__ int lix(int row, int col){
  return (row*64 + col) ^ ((row & 7) << 3);
}

// ---------------- small init kernels ----------------

__global__ __launch_bounds__(256) void k_tables(float2* tW, float2* tH, float2* tAB){
  int i = blockIdx.x*256 + threadIdx.x;
  const float PI2 = 6.28318530717958647692f;
  if (i < NWF*56){
    int k = i / 56, w = i % 56;
    float a = PI2 * (float)((k*w) % 56) * (1.0f/56.0f);
    tW[i] = make_float2(cosf(a), sinf(a));
  } else if (i < NWF*56 + 56*56){
    int j = i - NWF*56;
    int k = j / 56, h = j % 56;
    float a = PI2 * (float)((k*h) % 56) * (1.0f/56.0f);
    tH[j] = make_float2(cosf(a), sinf(a));
  } else if (i < NWF*56 + 56*56 + 56*NWF){
    int j = i - (NWF*56 + 56*56);
    int w = j / NWF, k = j % NWF;
    float al, be;
    if (k == 0)       { al = 1.0f; be = 0.0f; }
    else if (k == 28) { al = (w & 1) ? -1.0f : 1.0f; be = 0.0f; }
    else {
      float a = PI2 * (float)((k*w) % 56) * (1.0f/56.0f);
      al = 2.0f*cosf(a); be = -2.0f*sinf(a);
    }
    tAB[j] = make_float2(al, be);
  }
}

__global__ __launch_bounds__(256) void k_wt(const float* __restrict__ w, u16* __restrict__ wt, int K, int N){
  int i = blockIdx.x*256 + threadIdx.x;
  if (i >= K*N) return;
  int k = i / N, n = i % N;
  wt[(size_t)n*K + k] = f2bf(w[i]);
}

// ---------------- routing ----------------

__global__ __launch_bounds__(384) void k_gpart(const float* __restrict__ x, float* __restrict__ gp){
  int d = threadIdx.x, h = blockIdx.x, b = blockIdx.y;
  const float* xp = x + ((size_t)(b*NH + h)*NW)*NDIM + d;
  float s = 0.f;
  for (int w = 0; w < NW; ++w) s += xp[(size_t)w*NDIM];
  gp[(size_t)(b*NH + h)*NDIM + d] = s;
}

__global__ __launch_bounds__(384) void k_gfinal(const float* __restrict__ gp, float* __restrict__ g){
  int d = threadIdx.x, b = blockIdx.x;
  float s = 0.f;
  for (int h = 0; h < NH; ++h) s += gp[(size_t)(b*NH + h)*NDIM + d];
  g[b*NDIM + d] = s * (1.0f/3136.0f);
}

__global__ __launch_bounds__(128) void k_rmlp1(const float* __restrict__ g,
    const float* __restrict__ w_r1, const float* __restrict__ rs, const float* __restrict__ rb,
    float* __restrict__ hbuf){
  int b = blockIdx.x, t = threadIdx.x;
  __shared__ float lg[NDIM];
  for (int i = t; i < NDIM; i += 128) lg[i] = g[b*NDIM + i];
  __syncthreads();
  if (t < NRH){
    float a = 0.f;
    #pragma unroll 8
    for (int d = 0; d < NDIM; ++d) a = fmaf(lg[d], w_r1[d*NRH + t], a);
    float r = fmaxf(a, 0.f);
    hbuf[b*NRH + t] = rs[0]*r*r + rb[0];
  }
}

__global__ __launch_bounds__(256) void k_rmlp2(const float* __restrict__ hbuf,
    const float* __restrict__ w_r2, float* __restrict__ rout){
  int b = blockIdx.y;
  int c = blockIdx.x*256 + threadIdx.x;
  __shared__ float lh[NRH];
  if (threadIdx.x < NRH) lh[threadIdx.x] = hbuf[b*NRH + threadIdx.x];
  __syncthreads();
  float a0 = 0.f, a1 = 0.f, a2 = 0.f, a3 = 0.f;
  #pragma unroll 4
  for (int i = 0; i < NRH; ++i){
    float hv = lh[i];
    const float* wp = w_r2 + (size_t)i*(NFIL*NMED) + c;
    a0 = fmaf(hv, wp[0*NMED], a0);
    a1 = fmaf(hv, wp[1*NMED], a1);
    a2 = fmaf(hv, wp[2*NMED], a2);
    a3 = fmaf(hv, wp[3*NMED], a3);
  }
  float m = fmaxf(fmaxf(a0, a1), fmaxf(a2, a3));
  float e0 = expf(a0-m), e1 = expf(a1-m), e2 = expf(a2-m), e3 = expf(a3-m);
  float inv = 1.0f/(e0+e1+e2+e3);
  rout[(b*NFIL+0)*NMED + c] = e0*inv;
  rout[(b*NFIL+1)*NMED + c] = e1*inv;
  rout[(b*NFIL+2)*NMED + c] = e2*inv;
  rout[(b*NFIL+3)*NMED + c] = e3*inv;
}

// ---------------- bf16 MFMA GEMM: C[M,N] = A[M,K] * BT[N,K]^T ----------------

template<int EPI, typename TA>
__global__ __launch_bounds__(256) void gemm_bt(const TA* __restrict__ A, const u16* __restrict__ BT,
    float* __restrict__ Cf, u16* __restrict__ Cb, int M, int N, int K,
    const float* __restrict__ scp, const float* __restrict__ bip){
  __shared__ __align__(16) u16 lA[128*40];
  __shared__ __align__(16) u16 lB[128*40];
  int t = threadIdx.x;
  int m0 = blockIdx.x*128, n0 = blockIdx.y*128;
  int lane = t & 63, wid = t >> 6;
  int wr = (wid >> 1) * 64, wc = (wid & 1) * 64;
  int lr = lane & 15, kg = lane >> 4;
  f32x4 acc[4][4] = {};

  for (int k0 = 0; k0 < K; k0 += 32){
    #pragma unroll
    for (int j = 0; j < 2; ++j){
      int q = t + 256*j;
      int row = q >> 2, seg = q & 3;
      if constexpr (sizeof(TA) == 4){
        const float* ap = (const float*)(A + (size_t)(m0+row)*K + k0 + seg*8);
        float4 f0 = *(const float4*)ap;
        float4 f1 = *(const float4*)(ap + 4);
        union { s16x8 v8; int4 i4; } u;
        u.v8[0]=(short)f2bf(f0.x); u.v8[1]=(short)f2bf(f0.y);
        u.v8[2]=(short)f2bf(f0.z); u.v8[3]=(short)f2bf(f0.w);
        u.v8[4]=(short)f2bf(f1.x); u.v8[5]=(short)f2bf(f1.y);
        u.v8[6]=(short)f2bf(f1.z); u.v8[7]=(short)f2bf(f1.w);
        *(int4*)(&lA[row*40 + seg*8]) = u.i4;
      } else {
        *(int4*)(&lA[row*40 + seg*8]) = *(const int4*)(A + (size_t)(m0+row)*K + k0 + seg*8);
      }
      *(int4*)(&lB[row*40 + seg*8]) = *(const int4*)(&BT[(size_t)(n0+row)*K + k0 + seg*8]);
    }
    __syncthreads();
    s16x8 af[4], bf[4];
    #pragma unroll
    for (int fm = 0; fm < 4; ++fm) af[fm] = *(const s16x8*)(&lA[(wr + fm*16 + lr)*40 + kg*8]);
    #pragma unroll
    for (int fn = 0; fn < 4; ++fn) bf[fn] = *(const s16x8*)(&lB[(wc + fn*16 + lr)*40 + kg*8]);
    #pragma unroll
    for (int fm = 0; fm < 4; ++fm)
      #pragma unroll
      for (int fn = 0; fn < 4; ++fn)
        acc[fm][fn] = __builtin_amdgcn_mfma_f32_16x16x32_bf16(af[fm], bf[fn], acc[fm][fn], 0, 0, 0);
    __syncthreads();
  }

  float sc = 0.f, bi = 0.f;
  if (EPI == 0){ sc = scp[0]; bi = bip[0]; }
  #pragma unroll
  for (int fm = 0; fm < 4; ++fm)
    #pragma unroll
    for (int fn = 0; fn < 4; ++fn)
      #pragma unroll
      for (int r = 0; r < 4; ++r){
        int gm = m0 + wr + fm*16 + kg*4 + r;
        int gn = n0 + wc + fn*16 + lr;
        float val = acc[fm][fn][r];
        if (EPI == 0){
          float rl = fmaxf(val, 0.f);
          val = fmaf(sc*rl, rl, bi);
          Cb[(size_t)gm*N + gn] = f2bf(val);
        } else {
          Cf[(size_t)gm*N + gn] = val;
        }
      }
}

// ---------------- depthwise 3x3 conv + BN partials ----------------

__global__ __launch_bounds__(256) void k_dwconv(const u16* __restrict__ v, const float* __restrict__ kw,
    const float* __restrict__ kb, u16* __restrict__ locraw,
    float* __restrict__ psum, float* __restrict__ psq){
  int t = threadIdx.x;
  int cc = blockIdx.x, y = blockIdx.y, b = blockIdx.z;
  int c = cc*256 + t;
  float k00 = kw[0*NMED+c], k01 = kw[1*NMED+c], k02 = kw[2*NMED+c];
  float k10 = kw[3*NMED+c], k11 = kw[4*NMED+c], k12 = kw[5*NMED+c];
  float k20 = kw[6*NMED+c], k21 = kw[7*NMED+c], k22 = kw[8*NMED+c];
  float bias = kb[c];
  bool v0 = (y-1) >= 0, v2 = (y+1) < NH;
  const u16* r0 = v + ((size_t)((b*NH + y-1)*NW))*NMED + c;
  const u16* r1 = v + ((size_t)((b*NH + y  )*NW))*NMED + c;
  const u16* r2 = v + ((size_t)((b*NH + y+1)*NW))*NMED + c;
  auto L0 = [&](int x)->float{ return v0 ? bf2f(r0[(size_t)x*NMED]) : 0.f; };
  auto L1 = [&](int x)->float{ return bf2f(r1[(size_t)x*NMED]); };
  auto L2 = [&](int x)->float{ return v2 ? bf2f(r2[(size_t)x*NMED]) : 0.f; };
  float a0 = 0.f, a1 = 0.f, a2 = 0.f;
  float b0 = L0(0), b1 = L1(0), b2 = L2(0);
  float c0 = L0(1), c1 = L1(1), c2 = L2(1);
  float sum = 0.f, sq = 0.f;
  u16* op = locraw + ((size_t)(b*NH + y)*NW)*NMED + c;
  for (int x = 0; x < NW; ++x){
    float o = bias;
    o = fmaf(a0,k00, fmaf(b0,k01, fmaf(c0,k02, o)));
    o = fmaf(a1,k10, fmaf(b1,k11, fmaf(c1,k12, o)));
    o = fmaf(a2,k20, fmaf(b2,k21, fmaf(c2,k22, o)));
    op[(size_t)x*NMED] = f2bf(o);
    sum += o; sq = fmaf(o, o, sq);
    a0 = b0; a1 = b1; a2 = b2;
    b0 = c0; b1 = c1; b2 = c2;
    if (x+2 < NW){ c0 = L0(x+2); c1 = L1(x+2); c2 = L2(x+2); }
    else { c0 = 0.f; c1 = 0.f; c2 = 0.f; }
  }
  psum[(size_t)(b*NH + y)*NMED + c] = sum;
  psq [(size_t)(b*NH + y)*NMED + c] = sq;
}

__global__ __launch_bounds__(256) void k_bnstats(const float* __restrict__ psum, const float* __restrict__ psq,
    const float* __restrict__ gamma, const float* __restrict__ beta,
    float* __restrict__ bnsc, float* __restrict__ bnsh){
  int c = blockIdx.x*256 + threadIdx.x;
  if (c >= NMED) return;
  float s = 0.f, q = 0.f;
  for (int j = 0; j < NB*NH; ++j){ s += psum[(size_t)j*NMED + c]; q += psq[(size_t)j*NMED + c]; }
  float mu  = s * (1.0f/(float)NPIX);
  float var = q * (1.0f/(float)NPIX) - mu*mu;
  float sc = gamma[c] * rsqrtf(var + 1e-5f);
  bnsc[c] = sc;
  bnsh[c] = beta[c] - mu*sc;
}

// ---------------- spectral stages ----------------
// A1p packs (re,im) bf16 into one u32 per element: lo16=re, hi16=im.

// forward rDFT along W: A1p[bz][k2][h][c] = sum_w v[bz,h,w,c] * e^{-2pi i k2 w/56}
__global__ __launch_bounds__(256) void k_fftW(const u16* __restrict__ v,
    u32* __restrict__ A1p, const float2* __restrict__ tW){
  int t = threadIdx.x;
  int cc = blockIdx.x, h = blockIdx.y, bz = blockIdx.z;
  int c = cc*256 + t;
  __shared__ u16 lV[56*256];          // 28672 B
  __shared__ float2 tWs[NWF*56];      // 12992 B
  const u16* vp = v + ((size_t)(bz*NH + h)*NW)*NMED + c;
  for (int w = 0; w < 56; ++w) lV[w*256 + t] = vp[(size_t)w*NMED];
  for (int j = t; j < NWF*56; j += 256) tWs[j] = tW[j];
  __syncthreads();
  for (int k2 = 0; k2 < NWF; ++k2){
    float sr = 0.f, si = 0.f;
    const float2* tw = tWs + k2*56;
    for (int w = 0; w < 56; ++w){
      float f = bf2f(lV[w*256 + t]);
      float2 cs = tw[w];
      sr = fmaf(f,  cs.x, sr);
      si = fmaf(f, -cs.y, si);
    }
    size_t oi = ((size_t)(bz*NWF + k2)*NH + h)*NMED + c;
    A1p[oi] = packbf(sr, si);
  }
}

// Fused H-stage via MFMA: P = E_f X ; P' = P .* W /3136 ; Q = E_i P'. In-place on A1p.
// Block: (128 channels, k2, bz). LDS: C,S twiddles (A-layout), Xr/Xi (B-layout, reused for P').
__global__ __launch_bounds__(256) void k_ffth_fused(u32* __restrict__ A1p,
    const float2* __restrict__ tH, const float* __restrict__ rout, const float* __restrict__ cw){
  __shared__ u16 sC[64*64], sS[64*64];     // 8 KB each
  __shared__ u16 sXr[128*64], sXi[128*64]; // 16 KB each (X, then P')
  __shared__ float cwS[56*8];              // 1792 B
  int t = threadIdx.x;
  int cs = blockIdx.x, k2 = blockIdx.y, bz = blockIdx.z;
  size_t gbase = ((size_t)(bz*NWF + k2)*NH)*NMED + (size_t)cs*128;

  // ---- stage C,S twiddle matrices (bf16, zero-padded to 64x64) ----
  {
    int m = t >> 2;
    int kb = (t & 3) * 16;
    #pragma unroll
    for (int q = 0; q < 4; ++q){
      ushort4 cv, sv;
      #pragma unroll
      for (int j = 0; j < 4; ++j){
        int k = kb + q*4 + j;
        float cx = 0.f, sx = 0.f;
        if (m < 56 && k < 56){ float2 tv = tH[m*56 + k]; cx = tv.x; sx = tv.y; }
        ((u16*)&cv)[j] = f2bf(cx);
        ((u16*)&sv)[j] = f2bf(sx);
      }
      *(ushort4*)&sC[lix(m, kb + q*4)] = cv;
      *(ushort4*)&sS[lix(m, kb + q*4)] = sv;
    }
  }
  // ---- stage cw slice for this k2 ----
  for (int j = t; j < 56*8; j += 256){
    int k1 = j >> 3, f = j & 7;
    cwS[j] = cw[((size_t)(k1*NWF + k2))*8 + f];
  }
  // ---- stage X: split packed u32 into Xr/Xi bf16, layout [c][h] swizzled ----
  {
    int c = t & 127;
    int hb = (t >> 7) * 32;
    #pragma unroll
    for (int q = 0; q < 8; ++q){
      int h = hb + q*4;
      u32 u0=0, u1=0, u2=0, u3=0;
      if (h < 56){   // chunks never straddle 56 (56 % 4 == 0)
        const u32* gp = &A1p[gbase + (size_t)h*NMED + c];
        u0 = gp[0*NMED]; u1 = gp[1*NMED]; u2 = gp[2*NMED]; u3 = gp[3*NMED];
      }
      uint2 rr, ii;
      rr.x = (u0 & 0xffffu) | (u1 << 16);
      rr.y = (u2 & 0xffffu) | (u3 << 16);
      ii.x = (u0 >> 16) | (u1 & 0xffff0000u);
      ii.y = (u2 >> 16) | (u3 & 0xffff0000u);
      *(uint2*)&sXr[lix(c, h)] = rr;
      *(uint2*)&sXi[lix(c, h)] = ii;
    }
  }
  __syncthreads();

  int lane = t & 63, wid = t >> 6;
  int lr = lane & 15, kg = lane >> 4;
  int wn0 = wid * 32;

  f32x4 aR[4][2], aI[4][2];
  #pragma unroll
  for (int mi = 0; mi < 4; ++mi)
    #pragma unroll
    for (int ni = 0; ni < 2; ++ni){ aR[mi][ni] = (f32x4){0,0,0,0}; aI[mi][ni] = (f32x4){0,0,0,0}; }

  // ---- transform 1: P = (C - iS) (Xr + iXi) ----
  #pragma unroll
  for (int ks = 0; ks < 2; ++ks){
    int k0 = ks*32 + kg*8;
    s16x8 fC[4], fS[4];
    #pragma unroll
    for (int mi = 0; mi < 4; ++mi){
      fC[mi] = *(const s16x8*)&sC[lix(mi*16 + lr, k0)];
      fS[mi] = *(const s16x8*)&sS[lix(mi*16 + lr, k0)];
    }
    #pragma unroll
    for (int ni = 0; ni < 2; ++ni){
      s16x8 xr = *(const s16x8*)&sXr[lix(wn0 + ni*16 + lr, k0)];
      s16x8 xi = *(const s16x8*)&sXi[lix(wn0 + ni*16 + lr, k0)];
      uint4 xu = *(uint4*)&xr;
      xu.x ^= 0x80008000u; xu.y ^= 0x80008000u; xu.z ^= 0x80008000u; xu.w ^= 0x80008000u;
      s16x8 xrn = *(s16x8*)&xu;
      #pragma unroll
      for (int mi = 0; mi < 4; ++mi){
        aR[mi][ni] = __builtin_amdgcn_mfma_f32_16x16x32_bf16(fC[mi], xr,  aR[mi][ni], 0,0,0);
        aR[mi][ni] = __builtin_amdgcn_mfma_f32_16x16x32_bf16(fS[mi], xi,  aR[mi][ni], 0,0,0);
        aI[mi][ni] = __builtin_amdgcn_mfma_f32_16x16x32_bf16(fC[mi], xi,  aI[mi][ni], 0,0,0);
        aI[mi][ni] = __builtin_amdgcn_mfma_f32_16x16x32_bf16(fS[mi], xrn, aI[mi][ni], 0,0,0);
      }
    }
  }
  __syncthreads();   // all X reads complete before overwrite with P'

  // ---- W multiply (fp32) + store P' into sXr/sXi, layout [c][k1] ----
  const float inv = 1.0f/3136.0f;
  float rv0[2], rv1[2], rv2[2], rv3[2];
  #pragma unroll
  for (int ni = 0; ni < 2; ++ni){
    int cg = cs*128 + wn0 + ni*16 + lr;
    rv0[ni] = rout[(bz*NFIL+0)*NMED + cg];
    rv1[ni] = rout[(bz*NFIL+1)*NMED + cg];
    rv2[ni] = rout[(bz*NFIL+2)*NMED + cg];
    rv3[ni] = rout[(bz*NFIL+3)*NMED + cg];
  }
  #pragma unroll
  for (int mi = 0; mi < 4; ++mi){
    #pragma unroll
    for (int r = 0; r < 4; ++r){
      int k1 = mi*16 + kg*4 + r;
      float c0=0,c1=0,c2=0,c3=0,c4=0,c5=0,c6=0,c7=0;
      if (k1 < 56){
        const float* cp = cwS + k1*8;
        c0=cp[0]; c1=cp[1]; c2=cp[2]; c3=cp[3]; c4=cp[4]; c5=cp[5]; c6=cp[6]; c7=cp[7];
      }
      #pragma unroll
      for (int ni = 0; ni < 2; ++ni){
        float wr = rv0[ni]*c0 + rv1[ni]*c2 + rv2[ni]*c4 + rv3[ni]*c6;
        float wi = rv0[ni]*c1 + rv1[ni]*c3 + rv2[ni]*c5 + rv3[ni]*c7;
        float pr = aR[mi][ni][r], pi = aI[mi][ni][r];
        float qr = (pr*wr - pi*wi) * inv;
        float qi = (pr*wi + pi*wr) * inv;
        int cl = wn0 + ni*16 + lr;
        sXr[lix(cl, k1)] = f2bf(qr);
        sXi[lix(cl, k1)] = f2bf(qi);
      }
    }
  }
  __syncthreads();

  // ---- transform 2: Q = (C + iS) (P'r + iP'i) ----
  #pragma unroll
  for (int mi = 0; mi < 4; ++mi)
    #pragma unroll
    for (int ni = 0; ni < 2; ++ni){ aR[mi][ni] = (f32x4){0,0,0,0}; aI[mi][ni] = (f32x4){0,0,0,0}; }
  #pragma unroll
  for (int ks = 0; ks < 2; ++ks){
    int k0 = ks*32 + kg*8;
    s16x8 fC[4], fS[4];
    #pragma unroll
    for (int mi = 0; mi < 4; ++mi){
      fC[mi] = *(const s16x8*)&sC[lix(mi*16 + lr, k0)];
      fS[mi] = *(const s16x8*)&sS[lix(mi*16 + lr, k0)];
    }
    #pragma unroll
    for (int ni = 0; ni < 2; ++ni){
      s16x8 pr = *(const s16x8*)&sXr[lix(wn0 + ni*16 + lr, k0)];
      s16x8 pi = *(const s16x8*)&sXi[lix(wn0 + ni*16 + lr, k0)];
      uint4 pu = *(uint4*)&pi;
      pu.x ^= 0x80008000u; pu.y ^= 0x80008000u; pu.z ^= 0x80008000u; pu.w ^= 0x80008000u;
      s16x8 pin = *(s16x8*)&pu;
      #pragma unroll
      for (int mi = 0; mi < 4; ++mi){
        aR[mi][ni] = __builtin_amdgcn_mfma_f32_16x16x32_bf16(fC[mi], pr,  aR[mi][ni], 0,0,0);
        aR[mi][ni] = __builtin_amdgcn_mfma_f32_16x16x32_bf16(fS[mi], pin, aR[mi][ni], 0,0,0);
        aI[mi][ni] = __builtin_amdgcn_mfma_f32_16x16x32_bf16(fC[mi], pi,  aI[mi][ni], 0,0,0);
        aI[mi][ni] = __builtin_amdgcn_mfma_f32_16x16x32_bf16(fS[mi], pr,  aI[mi][ni], 0,0,0);
      }
    }
  }

  // ---- write Q back (packed bf16), rows n1 < 56 ----
  #pragma unroll
  for (int mi = 0; mi < 4; ++mi){
    #pragma unroll
    for (int r = 0; r < 4; ++r){
      int n1 = mi*16 + kg*4 + r;
      if (n1 < 56){
        #pragma unroll
        for (int ni = 0; ni < 2; ++ni){
          int cl = wn0 + ni*16 + lr;
          A1p[gbase + (size_t)n1*NMED + cl] = packbf(aR[mi][ni][r], aI[mi][ni][r]);
        }
      }
    }
  }
}

// inverse along W (Hermitian-folded, real) + BN-apply + StarReLU(loc) + add -> sbuf (bf16)
__global__ __launch_bounds__(256) void k_ifftW(const u32* __restrict__ Qp,
    const float2* __restrict__ tAB, const u16* __restrict__ locraw,
    const float* __restrict__ bnsc, const float* __restrict__ bnsh,
    const float* __restrict__ lsp, const float* __restrict__ lbp, u16* __restrict__ sbuf){
  int t = threadIdx.x;
  int cc = blockIdx.x, n1 = blockIdx.y, bz = blockIdx.z;
  int c = cc*256 + t;
  __shared__ u32 lq[NWF*256];         // 29696 B
  __shared__ float2 tABs[56*NWF];     // 12992 B
  for (int k2 = 0; k2 < NWF; ++k2){
    size_t qi = ((size_t)(bz*NWF + k2)*NH + n1)*NMED + c;
    lq[k2*256 + t] = Qp[qi];
  }
  for (int j = t; j < 56*NWF; j += 256) tABs[j] = tAB[j];
  __syncthreads();
  float bs = bnsc[c], bh = bnsh[c], ls = lsp[0], lb = lbp[0];
  for (int wc = 0; wc < 56; wc += 14){
    float acc[14];
    #pragma unroll
    for (int i = 0; i < 14; ++i) acc[i] = 0.f;
    for (int k2 = 0; k2 < NWF; ++k2){
      u32 u = lq[k2*256 + t];
      float qr = unpk_lo(u), qi = unpk_hi(u);
      #pragma unroll
      for (int i = 0; i < 14; ++i){
        float2 ab = tABs[(wc+i)*NWF + k2];
        acc[i] = fmaf(qr, ab.x, fmaf(qi, ab.y, acc[i]));
      }
    }
    #pragma unroll
    for (int i = 0; i < 14; ++i){
      int w = wc + i;
      size_t oi = ((size_t)(bz*NH + n1)*NW + w)*NMED + c;
      float lv = fmaf(bf2f(locraw[oi]), bs, bh);
      float rl = fmaxf(lv, 0.f);
      float loc = fmaf(ls*rl, rl, lb);
      sbuf[oi] = f2bf(acc[i] + loc);
    }
  }
}

// ---------------- host launch ----------------

extern "C" void kernel_launch(void* const* d_in, const int* in_sizes, int n_in,
                              void* d_out, int out_size, void* d_ws, size_t ws_size,
                              hipStream_t stream){
  const float* x       = (const float*)d_in[0];
  const float* w_pw1   = (const float*)d_in[1];
  const float* w_pw2   = (const float*)d_in[2];
  const float* a1s     = (const float*)d_in[3];
  const float* a1b     = (const float*)d_in[4];
  const float* w_r1    = (const float*)d_in[5];
  const float* r_s     = (const float*)d_in[6];
  const float* r_b     = (const float*)d_in[7];
  const float* w_r2    = (const float*)d_in[8];
  const float* dwk     = (const float*)d_in[9];
  const float* dwb     = (const float*)d_in[10];
  const float* bng     = (const float*)d_in[11];
  const float* bnb     = (const float*)d_in[12];
  const float* l_s     = (const float*)d_in[13];
  const float* l_b     = (const float*)d_in[14];
  const float* cw      = (const float*)d_in[15];
  float* out = (float*)d_out;

  char* ws = (char*)d_ws;
  size_t off = 0;
  auto al = [&](size_t n)->size_t{ off = (off + 255) & ~(size_t)255; size_t r = off; off += n; return r; };
  size_t o_tW  = al((size_t)NWF*56*sizeof(float2));
  size_t o_tH  = al((size_t)56*56*sizeof(float2));
  size_t o_tAB = al((size_t)56*NWF*sizeof(float2));
  size_t o_wT1 = al((size_t)NMED*NDIM*2);
  size_t o_wT2 = al((size_t)NDIM*NMED*2);
  size_t o_gp  = al((size_t)NB*NH*NDIM*4);
  size_t o_g   = al((size_t)NB*NDIM*4);
  size_t o_h   = al((size_t)NB*NRH*4);
  size_t o_rt  = al((size_t)NB*NFIL*NMED*4);
  size_t o_ps  = al((size_t)NB*NH*NMED*4);
  size_t o_pq  = al((size_t)NB*NH*NMED*4);
  size_t o_bs  = al((size_t)NMED*4);
  size_t o_bh  = al((size_t)NMED*4);
  size_t o_v   = al((size_t)NPIX*NMED*2);

  const size_t a1_per_batch = (size_t)NWF*NH*NMED*4;
  int CH = 16;
  size_t o_A1 = 0, need = 0;
  for (;;){
    size_t o2 = off;
    auto al2 = [&](size_t n)->size_t{ o2 = (o2 + 255) & ~(size_t)255; size_t r = o2; o2 += n; return r; };
    o_A1 = al2((size_t)CH*a1_per_batch);
    need = o2;
    if (need <= ws_size || CH == 1) break;
    CH >>= 1;
  }
  if (need > ws_size) return;

  float2* tW  = (float2*)(ws + o_tW);
  float2* tH  = (float2*)(ws + o_tH);
  float2* tAB = (float2*)(ws + o_tAB);
  u16* wT1 = (u16*)(ws + o_wT1);
  u16* wT2 = (u16*)(ws + o_wT2);
  float* gp = (float*)(ws + o_gp);
  float* g  = (float*)(ws + o_g);
  float* hb = (float*)(ws + o_h);
  float* rt = (float*)(ws + o_rt);
  float* ps = (float*)(ws + o_ps);
  float* pq = (float*)(ws + o_pq);
  float* bs = (float*)(ws + o_bs);
  float* bh = (float*)(ws + o_bh);
  u16* v   = (u16*)(ws + o_v);
  u32* A1p = (u32*)(ws + o_A1);
  u16* lraw = (u16*)d_out;

  int ntab = NWF*56 + 56*56 + 56*NWF;
  k_tables<<<(ntab+255)/256, 256, 0, stream>>>(tW, tH, tAB);
  k_wt<<<(NDIM*NMED+255)/256, 256, 0, stream>>>(w_pw1, wT1, NDIM, NMED);
  k_wt<<<(NMED*NDIM+255)/256, 256, 0, stream>>>(w_pw2, wT2, NMED, NDIM);

  k_gpart<<<dim3(NH, NB), 384, 0, stream>>>(x, gp);
  k_gfinal<<<NB, 384, 0, stream>>>(gp, g);
  k_rmlp1<<<NB, 128, 0, stream>>>(g, w_r1, r_s, r_b, hb);
  k_rmlp2<<<dim3(NMED/256, NB), 256, 0, stream>>>(hb, w_r2, rt);

  gemm_bt<0, float><<<dim3(NPIX/128, NMED/128), 256, 0, stream>>>(x, wT1, nullptr, v,
      NPIX, NMED, NDIM, a1s, a1b);

  k_dwconv<<<dim3(3, NH, NB), 256, 0, stream>>>(v, dwk, dwb, lraw, ps, pq);
  k_bnstats<<<3, 256, 0, stream>>>(ps, pq, bng, bnb, bs, bh);

  for (int b0 = 0; b0 < NB; b0 += CH){
    size_t pixoff = (size_t)b0*NH*NW*NMED;
    k_fftW       <<<dim3(3, NH,  CH), 256, 0, stream>>>(v + pixoff, A1p, tW);
    k_ffth_fused <<<dim3(NMED/128, NWF, CH), 256, 0, stream>>>(A1p, tH, rt + (size_t)b0*NFIL*NMED, cw);
    k_ifftW      <<<dim3(3, NH,  CH), 256, 0, stream>>>(A1p, tAB, lraw + pixoff, bs, bh,
                                                        l_s, l_b, v + pixoff);
  }

  gemm_bt<1, u16><<<dim3(NPIX/128, NDIM/128), 256, 0, stream>>>(v, wT2, out, nullptr,
      NPIX, NDIM, NMED, nullptr, nullptr);
}

// Round 6
// 599.512 us; speedup vs baseline: 2.4637x; 1.1941x over previous
//
#include <hip/hip_runtime.h>
#include <hip/hip_bf16.h>
#include <cstdint>
#include <cstddef>

typedef unsigned short u16;
typedef unsigned int u32;
using f32x4 = __attribute__((ext_vector_type(4))) float;
using s16x8 = __attribute__((ext_vector_type(8))) short;

#define NB   16
#define NH   56
#define NW   56
#define NDIM 384
#define NMED 768
#define NFIL 4
#define NRH  96
#define NWF  29
#define NPIX (NB*NH*NW)   // 50176

__device__ __forceinline__ float bf2f(u16 u){
  union { float f; u32 i; } w; w.i = ((u32)u) << 16; return w.f;
}
__device__ __forceinline__ u16 f2bf(float f){
  union { float f; u32 i; } w; w.f = f;
  u32 i = w.i;
  return (u16)((i + 0x7fffu + ((i >> 16) & 1u)) >> 16);
}
__device__ __forceinline__ u32 packbf(float r, float i){
  return (u32)f2bf(r) | ((u32)f2bf(i) << 16);
}
__device__ __forceinline__ float unpk_lo(u32 u){
  union { float f; u32 i; } w; w.i = u << 16; return w.f;
}
__device__ __forceinline__ float unpk_hi(u32 u){
  union { float f; u32 i; } w; w.i = u & 0xffff0000u; return w.f;
}
// swizzled LDS index for [row][col64] bf16 tiles (breaks 128B-stride bank conflicts)
__device__ __forceinline__ int lix(int row, int col){
  return (row*64 + col) ^ ((row & 7) << 3);
}

// ---------------- small init kernels ----------------

__global__ __launch_bounds__(256) void k_tables(float2* tW, float2* tH, float2* tAB){
  int i = blockIdx.x*256 + threadIdx.x;
  const float PI2 = 6.28318530717958647692f;
  if (i < NWF*56){
    int k = i / 56, w = i % 56;
    float a = PI2 * (float)((k*w) % 56) * (1.0f/56.0f);
    tW[i] = make_float2(cosf(a), sinf(a));
  } else if (i < NWF*56 + 56*56){
    int j = i - NWF*56;
    int k = j / 56, h = j % 56;
    float a = PI2 * (float)((k*h) % 56) * (1.0f/56.0f);
    tH[j] = make_float2(cosf(a), sinf(a));
  } else if (i < NWF*56 + 56*56 + 56*NWF){
    int j = i - (NWF*56 + 56*56);
    int w = j / NWF, k = j % NWF;
    float al, be;
    if (k == 0)       { al = 1.0f; be = 0.0f; }
    else if (k == 28) { al = (w & 1) ? -1.0f : 1.0f; be = 0.0f; }
    else {
      float a = PI2 * (float)((k*w) % 56) * (1.0f/56.0f);
      al = 2.0f*cosf(a); be = -2.0f*sinf(a);
    }
    tAB[j] = make_float2(al, be);
  }
}

__global__ __launch_bounds__(256) void k_wt(const float* __restrict__ w, u16* __restrict__ wt, int K, int N){
  int i = blockIdx.x*256 + threadIdx.x;
  if (i >= K*N) return;
  int k = i / N, n = i % N;
  wt[(size_t)n*K + k] = f2bf(w[i]);
}

// ---------------- routing ----------------

__global__ __launch_bounds__(384) void k_gpart(const float* __restrict__ x, float* __restrict__ gp){
  int d = threadIdx.x, h = blockIdx.x, b = blockIdx.y;
  const float* xp = x + ((size_t)(b*NH + h)*NW)*NDIM + d;
  float s = 0.f;
  for (int w = 0; w < NW; ++w) s += xp[(size_t)w*NDIM];
  gp[(size_t)(b*NH + h)*NDIM + d] = s;
}

__global__ __launch_bounds__(384) void k_gfinal(const float* __restrict__ gp, float* __restrict__ g){
  int d = threadIdx.x, b = blockIdx.x;
  float s = 0.f;
  for (int h = 0; h < NH; ++h) s += gp[(size_t)(b*NH + h)*NDIM + d];
  g[b*NDIM + d] = s * (1.0f/3136.0f);
}

__global__ __launch_bounds__(128) void k_rmlp1(const float* __restrict__ g,
    const float* __restrict__ w_r1, const float* __restrict__ rs, const float* __restrict__ rb,
    float* __restrict__ hbuf){
  int b = blockIdx.x, t = threadIdx.x;
  __shared__ float lg[NDIM];
  for (int i = t; i < NDIM; i += 128) lg[i] = g[b*NDIM + i];
  __syncthreads();
  if (t < NRH){
    float a = 0.f;
    #pragma unroll 8
    for (int d = 0; d < NDIM; ++d) a = fmaf(lg[d], w_r1[d*NRH + t], a);
    float r = fmaxf(a, 0.f);
    hbuf[b*NRH + t] = rs[0]*r*r + rb[0];
  }
}

__global__ __launch_bounds__(256) void k_rmlp2(const float* __restrict__ hbuf,
    const float* __restrict__ w_r2, float* __restrict__ rout){
  int b = blockIdx.y;
  int c = blockIdx.x*256 + threadIdx.x;
  __shared__ float lh[NRH];
  if (threadIdx.x < NRH) lh[threadIdx.x] = hbuf[b*NRH + threadIdx.x];
  __syncthreads();
  float a0 = 0.f, a1 = 0.f, a2 = 0.f, a3 = 0.f;
  #pragma unroll 4
  for (int i = 0; i < NRH; ++i){
    float hv = lh[i];
    const float* wp = w_r2 + (size_t)i*(NFIL*NMED) + c;
    a0 = fmaf(hv, wp[0*NMED], a0);
    a1 = fmaf(hv, wp[1*NMED], a1);
    a2 = fmaf(hv, wp[2*NMED], a2);
    a3 = fmaf(hv, wp[3*NMED], a3);
  }
  float m = fmaxf(fmaxf(a0, a1), fmaxf(a2, a3));
  float e0 = expf(a0-m), e1 = expf(a1-m), e2 = expf(a2-m), e3 = expf(a3-m);
  float inv = 1.0f/(e0+e1+e2+e3);
  rout[(b*NFIL+0)*NMED + c] = e0*inv;
  rout[(b*NFIL+1)*NMED + c] = e1*inv;
  rout[(b*NFIL+2)*NMED + c] = e2*inv;
  rout[(b*NFIL+3)*NMED + c] = e3*inv;
}

// ---------------- bf16 MFMA GEMM: C[M,N] = A[M,K] * BT[N,K]^T ----------------

template<int EPI, typename TA>
__global__ __launch_bounds__(256) void gemm_bt(const TA* __restrict__ A, const u16* __restrict__ BT,
    float* __restrict__ Cf, u16* __restrict__ Cb, int M, int N, int K,
    const float* __restrict__ scp, const float* __restrict__ bip){
  __shared__ __align__(16) u16 lA[128*40];
  __shared__ __align__(16) u16 lB[128*40];
  int t = threadIdx.x;
  int m0 = blockIdx.x*128, n0 = blockIdx.y*128;
  int lane = t & 63, wid = t >> 6;
  int wr = (wid >> 1) * 64, wc = (wid & 1) * 64;
  int lr = lane & 15, kg = lane >> 4;
  f32x4 acc[4][4] = {};

  for (int k0 = 0; k0 < K; k0 += 32){
    #pragma unroll
    for (int j = 0; j < 2; ++j){
      int q = t + 256*j;
      int row = q >> 2, seg = q & 3;
      if constexpr (sizeof(TA) == 4){
        const float* ap = (const float*)(A + (size_t)(m0+row)*K + k0 + seg*8);
        float4 f0 = *(const float4*)ap;
        float4 f1 = *(const float4*)(ap + 4);
        union { s16x8 v8; int4 i4; } u;
        u.v8[0]=(short)f2bf(f0.x); u.v8[1]=(short)f2bf(f0.y);
        u.v8[2]=(short)f2bf(f0.z); u.v8[3]=(short)f2bf(f0.w);
        u.v8[4]=(short)f2bf(f1.x); u.v8[5]=(short)f2bf(f1.y);
        u.v8[6]=(short)f2bf(f1.z); u.v8[7]=(short)f2bf(f1.w);
        *(int4*)(&lA[row*40 + seg*8]) = u.i4;
      } else {
        *(int4*)(&lA[row*40 + seg*8]) = *(const int4*)(A + (size_t)(m0+row)*K + k0 + seg*8);
      }
      *(int4*)(&lB[row*40 + seg*8]) = *(const int4*)(&BT[(size_t)(n0+row)*K + k0 + seg*8]);
    }
    __syncthreads();
    s16x8 af[4], bf[4];
    #pragma unroll
    for (int fm = 0; fm < 4; ++fm) af[fm] = *(const s16x8*)(&lA[(wr + fm*16 + lr)*40 + kg*8]);
    #pragma unroll
    for (int fn = 0; fn < 4; ++fn) bf[fn] = *(const s16x8*)(&lB[(wc + fn*16 + lr)*40 + kg*8]);
    #pragma unroll
    for (int fm = 0; fm < 4; ++fm)
      #pragma unroll
      for (int fn = 0; fn < 4; ++fn)
        acc[fm][fn] = __builtin_amdgcn_mfma_f32_16x16x32_bf16(af[fm], bf[fn], acc[fm][fn], 0, 0, 0);
    __syncthreads();
  }

  float sc = 0.f, bi = 0.f;
  if (EPI == 0){ sc = scp[0]; bi = bip[0]; }
  #pragma unroll
  for (int fm = 0; fm < 4; ++fm)
    #pragma unroll
    for (int fn = 0; fn < 4; ++fn)
      #pragma unroll
      for (int r = 0; r < 4; ++r){
        int gm = m0 + wr + fm*16 + kg*4 + r;
        int gn = n0 + wc + fn*16 + lr;
        float val = acc[fm][fn][r];
        if (EPI == 0){
          float rl = fmaxf(val, 0.f);
          val = fmaf(sc*rl, rl, bi);
          Cb[(size_t)gm*N + gn] = f2bf(val);
        } else {
          Cf[(size_t)gm*N + gn] = val;
        }
      }
}

// ---------------- depthwise 3x3 conv + BN partials ----------------

__global__ __launch_bounds__(256) void k_dwconv(const u16* __restrict__ v, const float* __restrict__ kw,
    const float* __restrict__ kb, u16* __restrict__ locraw,
    float* __restrict__ psum, float* __restrict__ psq){
  int t = threadIdx.x;
  int cc = blockIdx.x, y = blockIdx.y, b = blockIdx.z;
  int c = cc*256 + t;
  float k00 = kw[0*NMED+c], k01 = kw[1*NMED+c], k02 = kw[2*NMED+c];
  float k10 = kw[3*NMED+c], k11 = kw[4*NMED+c], k12 = kw[5*NMED+c];
  float k20 = kw[6*NMED+c], k21 = kw[7*NMED+c], k22 = kw[8*NMED+c];
  float bias = kb[c];
  bool v0 = (y-1) >= 0, v2 = (y+1) < NH;
  const u16* r0 = v + ((size_t)((b*NH + y-1)*NW))*NMED + c;
  const u16* r1 = v + ((size_t)((b*NH + y  )*NW))*NMED + c;
  const u16* r2 = v + ((size_t)((b*NH + y+1)*NW))*NMED + c;
  auto L0 = [&](int x)->float{ return v0 ? bf2f(r0[(size_t)x*NMED]) : 0.f; };
  auto L1 = [&](int x)->float{ return bf2f(r1[(size_t)x*NMED]); };
  auto L2 = [&](int x)->float{ return v2 ? bf2f(r2[(size_t)x*NMED]) : 0.f; };
  float a0 = 0.f, a1 = 0.f, a2 = 0.f;
  float b0 = L0(0), b1 = L1(0), b2 = L2(0);
  float c0 = L0(1), c1 = L1(1), c2 = L2(1);
  float sum = 0.f, sq = 0.f;
  u16* op = locraw + ((size_t)(b*NH + y)*NW)*NMED + c;
  for (int x = 0; x < NW; ++x){
    float o = bias;
    o = fmaf(a0,k00, fmaf(b0,k01, fmaf(c0,k02, o)));
    o = fmaf(a1,k10, fmaf(b1,k11, fmaf(c1,k12, o)));
    o = fmaf(a2,k20, fmaf(b2,k21, fmaf(c2,k22, o)));
    op[(size_t)x*NMED] = f2bf(o);
    sum += o; sq = fmaf(o, o, sq);
    a0 = b0; a1 = b1; a2 = b2;
    b0 = c0; b1 = c1; b2 = c2;
    if (x+2 < NW){ c0 = L0(x+2); c1 = L1(x+2); c2 = L2(x+2); }
    else { c0 = 0.f; c1 = 0.f; c2 = 0.f; }
  }
  psum[(size_t)(b*NH + y)*NMED + c] = sum;
  psq [(size_t)(b*NH + y)*NMED + c] = sq;
}

__global__ __launch_bounds__(256) void k_bnstats(const float* __restrict__ psum, const float* __restrict__ psq,
    const float* __restrict__ gamma, const float* __restrict__ beta,
    float* __restrict__ bnsc, float* __restrict__ bnsh){
  int c = blockIdx.x*256 + threadIdx.x;
  if (c >= NMED) return;
  float s = 0.f, q = 0.f;
  for (int j = 0; j < NB*NH; ++j){ s += psum[(size_t)j*NMED + c]; q += psq[(size_t)j*NMED + c]; }
  float mu  = s * (1.0f/(float)NPIX);
  float var = q * (1.0f/(float)NPIX) - mu*mu;
  float sc = gamma[c] * rsqrtf(var + 1e-5f);
  bnsc[c] = sc;
  bnsh[c] = beta[c] - mu*sc;
}

// ---------------- spectral stages (all MFMA) ----------------
// A1p packs (re,im) bf16 into one u32 per element: lo16=re, hi16=im.

// forward rDFT along W via MFMA: A1p[bz][k2][h][c] = sum_w v[bz,h,w,c] e^{-2pi i k2 w/56}
// A = E[64j x 64w] (j=2k2: cos, j=2k2+1: -sin), B = v-tile [128c x 64w].
__global__ __launch_bounds__(256) void k_fftw_mfma(const u16* __restrict__ v,
    u32* __restrict__ A1p, const float2* __restrict__ tW){
  __shared__ u16 sE[64*64];   // 8 KB
  __shared__ u16 sV[128*64];  // 16 KB
  int t = threadIdx.x;
  int cs = blockIdx.x, h = blockIdx.y, bz = blockIdx.z;

  // stage E (zero-padded)
  {
    int j = t >> 2;
    int wb = (t & 3) * 16;
    int k2 = j >> 1;
    #pragma unroll
    for (int q = 0; q < 4; ++q){
      ushort4 ev;
      #pragma unroll
      for (int m = 0; m < 4; ++m){
        int w = wb + q*4 + m;
        float val = 0.f;
        if (k2 < NWF && w < 56){
          float2 tv = tW[k2*56 + w];
          val = (j & 1) ? -tv.y : tv.x;
        }
        ((u16*)&ev)[m] = f2bf(val);
      }
      *(ushort4*)&sE[lix(j, wb + q*4)] = ev;
    }
  }
  // stage V transposed: [c][w], coalesced int4 loads, b64 transposed writes
  {
    int cg = (t & 15) * 8;       // c base (8 contiguous)
    int wq = (t >> 4) * 4;       // w base (0..60)
    u16 buf[4][8];
    #pragma unroll
    for (int dw = 0; dw < 4; ++dw){
      int w = wq + dw;
      if (w < 56){
        *(int4*)&buf[dw][0] = *(const int4*)&v[((size_t)((bz*NH + h)*NW) + w)*NMED + (size_t)cs*128 + cg];
      } else {
        #pragma unroll
        for (int j = 0; j < 8; ++j) buf[dw][j] = 0;
      }
    }
    #pragma unroll
    for (int j = 0; j < 8; ++j){
      u16 tmp[4] = {buf[0][j], buf[1][j], buf[2][j], buf[3][j]};
      *(uint2*)&sV[lix(cg + j, wq)] = *(uint2*)tmp;
    }
  }
  __syncthreads();

  int lane = t & 63, wid = t >> 6;
  int lr = lane & 15, kg = lane >> 4;
  int wn0 = wid * 32;
  f32x4 acc[4][2] = {};

  #pragma unroll
  for (int ks = 0; ks < 2; ++ks){
    int k0 = ks*32 + kg*8;
    s16x8 fE[4];
    #pragma unroll
    for (int mi = 0; mi < 4; ++mi) fE[mi] = *(const s16x8*)&sE[lix(mi*16 + lr, k0)];
    #pragma unroll
    for (int ni = 0; ni < 2; ++ni){
      s16x8 bv = *(const s16x8*)&sV[lix(wn0 + ni*16 + lr, k0)];
      #pragma unroll
      for (int mi = 0; mi < 4; ++mi)
        acc[mi][ni] = __builtin_amdgcn_mfma_f32_16x16x32_bf16(fE[mi], bv, acc[mi][ni], 0, 0, 0);
    }
  }

  // rows j come in (re,im) adjacent pairs within each lane -> pack u32
  size_t gb = ((size_t)bz*NWF*NH)*NMED + (size_t)h*NMED + (size_t)cs*128;
  #pragma unroll
  for (int mi = 0; mi < 4; ++mi){
    #pragma unroll
    for (int rp = 0; rp < 2; ++rp){
      int j0 = mi*16 + kg*4 + rp*2;
      int k2 = j0 >> 1;
      if (k2 < NWF){
        #pragma unroll
        for (int ni = 0; ni < 2; ++ni){
          int c = wn0 + ni*16 + lr;
          A1p[gb + (size_t)k2*NH*NMED + c] = packbf(acc[mi][ni][rp*2], acc[mi][ni][rp*2+1]);
        }
      }
    }
  }
}

// Fused H-stage via MFMA: P = E_f X ; P' = P .* W /3136 ; Q = E_i P'. In-place on A1p.
__global__ __launch_bounds__(256) void k_ffth_fused(u32* __restrict__ A1p,
    const float2* __restrict__ tH, const float* __restrict__ rout, const float* __restrict__ cw){
  __shared__ u16 sC[64*64], sS[64*64];     // 8 KB each
  __shared__ u16 sXr[128*64], sXi[128*64]; // 16 KB each (X, then P')
  __shared__ float cwS[56*8];              // 1792 B
  int t = threadIdx.x;
  int cs = blockIdx.x, k2 = blockIdx.y, bz = blockIdx.z;
  size_t gbase = ((size_t)(bz*NWF + k2)*NH)*NMED + (size_t)cs*128;

  {
    int m = t >> 2;
    int kb = (t & 3) * 16;
    #pragma unroll
    for (int q = 0; q < 4; ++q){
      ushort4 cv, sv;
      #pragma unroll
      for (int j = 0; j < 4; ++j){
        int k = kb + q*4 + j;
        float cx = 0.f, sx = 0.f;
        if (m < 56 && k < 56){ float2 tv = tH[m*56 + k]; cx = tv.x; sx = tv.y; }
        ((u16*)&cv)[j] = f2bf(cx);
        ((u16*)&sv)[j] = f2bf(sx);
      }
      *(ushort4*)&sC[lix(m, kb + q*4)] = cv;
      *(ushort4*)&sS[lix(m, kb + q*4)] = sv;
    }
  }
  for (int j = t; j < 56*8; j += 256){
    int k1 = j >> 3, f = j & 7;
    cwS[j] = cw[((size_t)(k1*NWF + k2))*8 + f];
  }
  {
    int c = t & 127;
    int hb = (t >> 7) * 32;
    #pragma unroll
    for (int q = 0; q < 8; ++q){
      int h = hb + q*4;
      u32 u0=0, u1=0, u2=0, u3=0;
      if (h < 56){
        const u32* gp = &A1p[gbase + (size_t)h*NMED + c];
        u0 = gp[0*NMED]; u1 = gp[1*NMED]; u2 = gp[2*NMED]; u3 = gp[3*NMED];
      }
      uint2 rr, ii;
      rr.x = (u0 & 0xffffu) | (u1 << 16);
      rr.y = (u2 & 0xffffu) | (u3 << 16);
      ii.x = (u0 >> 16) | (u1 & 0xffff0000u);
      ii.y = (u2 >> 16) | (u3 & 0xffff0000u);
      *(uint2*)&sXr[lix(c, h)] = rr;
      *(uint2*)&sXi[lix(c, h)] = ii;
    }
  }
  __syncthreads();

  int lane = t & 63, wid = t >> 6;
  int lr = lane & 15, kg = lane >> 4;
  int wn0 = wid * 32;

  f32x4 aR[4][2], aI[4][2];
  #pragma unroll
  for (int mi = 0; mi < 4; ++mi)
    #pragma unroll
    for (int ni = 0; ni < 2; ++ni){ aR[mi][ni] = (f32x4){0,0,0,0}; aI[mi][ni] = (f32x4){0,0,0,0}; }

  #pragma unroll
  for (int ks = 0; ks < 2; ++ks){
    int k0 = ks*32 + kg*8;
    s16x8 fC[4], fS[4];
    #pragma unroll
    for (int mi = 0; mi < 4; ++mi){
      fC[mi] = *(const s16x8*)&sC[lix(mi*16 + lr, k0)];
      fS[mi] = *(const s16x8*)&sS[lix(mi*16 + lr, k0)];
    }
    #pragma unroll
    for (int ni = 0; ni < 2; ++ni){
      s16x8 xr = *(const s16x8*)&sXr[lix(wn0 + ni*16 + lr, k0)];
      s16x8 xi = *(const s16x8*)&sXi[lix(wn0 + ni*16 + lr, k0)];
      uint4 xu = *(uint4*)&xr;
      xu.x ^= 0x80008000u; xu.y ^= 0x80008000u; xu.z ^= 0x80008000u; xu.w ^= 0x80008000u;
      s16x8 xrn = *(s16x8*)&xu;
      #pragma unroll
      for (int mi = 0; mi < 4; ++mi){
        aR[mi][ni] = __builtin_amdgcn_mfma_f32_16x16x32_bf16(fC[mi], xr,  aR[mi][ni], 0,0,0);
        aR[mi][ni] = __builtin_amdgcn_mfma_f32_16x16x32_bf16(fS[mi], xi,  aR[mi][ni], 0,0,0);
        aI[mi][ni] = __builtin_amdgcn_mfma_f32_16x16x32_bf16(fC[mi], xi,  aI[mi][ni], 0,0,0);
        aI[mi][ni] = __builtin_amdgcn_mfma_f32_16x16x32_bf16(fS[mi], xrn, aI[mi][ni], 0,0,0);
      }
    }
  }
  __syncthreads();

  const float inv = 1.0f/3136.0f;
  float rv0[2], rv1[2], rv2[2], rv3[2];
  #pragma unroll
  for (int ni = 0; ni < 2; ++ni){
    int cg = cs*128 + wn0 + ni*16 + lr;
    rv0[ni] = rout[(bz*NFIL+0)*NMED + cg];
    rv1[ni] = rout[(bz*NFIL+1)*NMED + cg];
    rv2[ni] = rout[(bz*NFIL+2)*NMED + cg];
    rv3[ni] = rout[(bz*NFIL+3)*NMED + cg];
  }
  #pragma unroll
  for (int mi = 0; mi < 4; ++mi){
    #pragma unroll
    for (int r = 0; r < 4; ++r){
      int k1 = mi*16 + kg*4 + r;
      float c0=0,c1=0,c2=0,c3=0,c4=0,c5=0,c6=0,c7=0;
      if (k1 < 56){
        const float* cp = cwS + k1*8;
        c0=cp[0]; c1=cp[1]; c2=cp[2]; c3=cp[3]; c4=cp[4]; c5=cp[5]; c6=cp[6]; c7=cp[7];
      }
      #pragma unroll
      for (int ni = 0; ni < 2; ++ni){
        float wr = rv0[ni]*c0 + rv1[ni]*c2 + rv2[ni]*c4 + rv3[ni]*c6;
        float wi = rv0[ni]*c1 + rv1[ni]*c3 + rv2[ni]*c5 + rv3[ni]*c7;
        float pr = aR[mi][ni][r], pi = aI[mi][ni][r];
        float qr = (pr*wr - pi*wi) * inv;
        float qi = (pr*wi + pi*wr) * inv;
        int cl = wn0 + ni*16 + lr;
        sXr[lix(cl, k1)] = f2bf(qr);
        sXi[lix(cl, k1)] = f2bf(qi);
      }
    }
  }
  __syncthreads();

  #pragma unroll
  for (int mi = 0; mi < 4; ++mi)
    #pragma unroll
    for (int ni = 0; ni < 2; ++ni){ aR[mi][ni] = (f32x4){0,0,0,0}; aI[mi][ni] = (f32x4){0,0,0,0}; }
  #pragma unroll
  for (int ks = 0; ks < 2; ++ks){
    int k0 = ks*32 + kg*8;
    s16x8 fC[4], fS[4];
    #pragma unroll
    for (int mi = 0; mi < 4; ++mi){
      fC[mi] = *(const s16x8*)&sC[lix(mi*16 + lr, k0)];
      fS[mi] = *(const s16x8*)&sS[lix(mi*16 + lr, k0)];
    }
    #pragma unroll
    for (int ni = 0; ni < 2; ++ni){
      s16x8 pr = *(const s16x8*)&sXr[lix(wn0 + ni*16 + lr, k0)];
      s16x8 pi = *(const s16x8*)&sXi[lix(wn0 + ni*16 + lr, k0)];
      uint4 pu = *(uint4*)&pi;
      pu.x ^= 0x80008000u; pu.y ^= 0x80008000u; pu.z ^= 0x80008000u; pu.w ^= 0x80008000u;
      s16x8 pin = *(s16x8*)&pu;
      #pragma unroll
      for (int mi = 0; mi < 4; ++mi){
        aR[mi][ni] = __builtin_amdgcn_mfma_f32_16x16x32_bf16(fC[mi], pr,  aR[mi][ni], 0,0,0);
        aR[mi][ni] = __builtin_amdgcn_mfma_f32_16x16x32_bf16(fS[mi], pin, aR[mi][ni], 0,0,0);
        aI[mi][ni] = __builtin_amdgcn_mfma_f32_16x16x32_bf16(fC[mi], pi,  aI[mi][ni], 0,0,0);
        aI[mi][ni] = __builtin_amdgcn_mfma_f32_16x16x32_bf16(fS[mi], pr,  aI[mi][ni], 0,0,0);
      }
    }
  }

  #pragma unroll
  for (int mi = 0; mi < 4; ++mi){
    #pragma unroll
    for (int r = 0; r < 4; ++r){
      int n1 = mi*16 + kg*4 + r;
      if (n1 < 56){
        #pragma unroll
        for (int ni = 0; ni < 2; ++ni){
          int cl = wn0 + ni*16 + lr;
          A1p[gbase + (size_t)n1*NMED + cl] = packbf(aR[mi][ni][r], aI[mi][ni][r]);
        }
      }
    }
  }
}

// inverse along W via MFMA (Hermitian-folded, real) + BN + StarReLU(loc) + add -> sbuf
// A = AB[64w x 64j] (j=2k2: alpha, j=2k2+1: beta), B = Q staged [128c x 64j].
__global__ __launch_bounds__(256) void k_ifftw_mfma(const u32* __restrict__ Qp,
    const float2* __restrict__ tAB, const u16* __restrict__ locraw,
    const float* __restrict__ bnsc, const float* __restrict__ bnsh,
    const float* __restrict__ lsp, const float* __restrict__ lbp, u16* __restrict__ sbuf){
  __shared__ u16 sA[64*64];    // 8 KB
  __shared__ u16 sQ[128*64];   // 16 KB
  int t = threadIdx.x;
  int cs = blockIdx.x, n1 = blockIdx.y, bz = blockIdx.z;

  // stage A from tAB[w*NWF + k2]
  {
    int w = t >> 2;
    int jb = (t & 3) * 16;
    #pragma unroll
    for (int q = 0; q < 4; ++q){
      ushort4 av;
      #pragma unroll
      for (int m = 0; m < 4; ++m){
        int j = jb + q*4 + m;
        int k2 = j >> 1;
        float val = 0.f;
        if (w < 56 && k2 < NWF){
          float2 ab = tAB[w*NWF + k2];
          val = (j & 1) ? ab.y : ab.x;
        }
        ((u16*)&av)[m] = f2bf(val);
      }
      *(ushort4*)&sA[lix(w, jb + q*4)] = av;
    }
  }
  // stage Q: packed (qr,qi) u32 is already the adjacent-pair layout for [c][2k2..2k2+1]
  {
    int c = t & 127;
    for (int k2 = (t >> 7); k2 < 32; k2 += 2){
      u32 qv = 0;
      if (k2 < NWF)
        qv = Qp[(((size_t)bz*NWF + k2)*NH + n1)*NMED + (size_t)cs*128 + c];
      *(u32*)&sQ[lix(c, 2*k2)] = qv;
    }
  }
  __syncthreads();

  int lane = t & 63, wid = t >> 6;
  int lr = lane & 15, kg = lane >> 4;
  int wn0 = wid * 32;
  f32x4 acc[4][2] = {};

  #pragma unroll
  for (int ks = 0; ks < 2; ++ks){
    int k0 = ks*32 + kg*8;
    s16x8 fA[4];
    #pragma unroll
    for (int mi = 0; mi < 4; ++mi) fA[mi] = *(const s16x8*)&sA[lix(mi*16 + lr, k0)];
    #pragma unroll
    for (int ni = 0; ni < 2; ++ni){
      s16x8 bq = *(const s16x8*)&sQ[lix(wn0 + ni*16 + lr, k0)];
      #pragma unroll
      for (int mi = 0; mi < 4; ++mi)
        acc[mi][ni] = __builtin_amdgcn_mfma_f32_16x16x32_bf16(fA[mi], bq, acc[mi][ni], 0, 0, 0);
    }
  }

  float ls = lsp[0], lb = lbp[0];
  size_t rowbase = ((size_t)(bz*NH + n1)*NW)*NMED + (size_t)cs*128;
  #pragma unroll
  for (int ni = 0; ni < 2; ++ni){
    int cl = wn0 + ni*16 + lr;
    float bsv = bnsc[cs*128 + cl], bhv = bnsh[cs*128 + cl];
    #pragma unroll
    for (int mi = 0; mi < 4; ++mi){
      #pragma unroll
      for (int r = 0; r < 4; ++r){
        int w = mi*16 + kg*4 + r;
        if (w < 56){
          size_t oi = rowbase + (size_t)w*NMED + cl;
          float lv = fmaf(bf2f(locraw[oi]), bsv, bhv);
          float rl = fmaxf(lv, 0.f);
          float loc = fmaf(ls*rl, rl, lb);
          sbuf[oi] = f2bf(acc[mi][ni][r] + loc);
        }
      }
    }
  }
}

// ---------------- host launch ----------------

extern "C" void kernel_launch(void* const* d_in, const int* in_sizes, int n_in,
                              void* d_out, int out_size, void* d_ws, size_t ws_size,
                              hipStream_t stream){
  const float* x       = (const float*)d_in[0];
  const float* w_pw1   = (const float*)d_in[1];
  const float* w_pw2   = (const float*)d_in[2];
  const float* a1s     = (const float*)d_in[3];
  const float* a1b     = (const float*)d_in[4];
  const float* w_r1    = (const float*)d_in[5];
  const float* r_s     = (const float*)d_in[6];
  const float* r_b     = (const float*)d_in[7];
  const float* w_r2    = (const float*)d_in[8];
  const float* dwk     = (const float*)d_in[9];
  const float* dwb     = (const float*)d_in[10];
  const float* bng     = (const float*)d_in[11];
  const float* bnb     = (const float*)d_in[12];
  const float* l_s     = (const float*)d_in[13];
  const float* l_b     = (const float*)d_in[14];
  const float* cw      = (const float*)d_in[15];
  float* out = (float*)d_out;

  char* ws = (char*)d_ws;
  size_t off = 0;
  auto al = [&](size_t n)->size_t{ off = (off + 255) & ~(size_t)255; size_t r = off; off += n; return r; };
  size_t o_tW  = al((size_t)NWF*56*sizeof(float2));
  size_t o_tH  = al((size_t)56*56*sizeof(float2));
  size_t o_tAB = al((size_t)56*NWF*sizeof(float2));
  size_t o_wT1 = al((size_t)NMED*NDIM*2);
  size_t o_wT2 = al((size_t)NDIM*NMED*2);
  size_t o_gp  = al((size_t)NB*NH*NDIM*4);
  size_t o_g   = al((size_t)NB*NDIM*4);
  size_t o_h   = al((size_t)NB*NRH*4);
  size_t o_rt  = al((size_t)NB*NFIL*NMED*4);
  size_t o_ps  = al((size_t)NB*NH*NMED*4);
  size_t o_pq  = al((size_t)NB*NH*NMED*4);
  size_t o_bs  = al((size_t)NMED*4);
  size_t o_bh  = al((size_t)NMED*4);
  size_t o_v   = al((size_t)NPIX*NMED*2);

  const size_t a1_per_batch = (size_t)NWF*NH*NMED*4;
  int CH = 16;
  size_t o_A1 = 0, need = 0;
  for (;;){
    size_t o2 = off;
    auto al2 = [&](size_t n)->size_t{ o2 = (o2 + 255) & ~(size_t)255; size_t r = o2; o2 += n; return r; };
    o_A1 = al2((size_t)CH*a1_per_batch);
    need = o2;
    if (need <= ws_size || CH == 1) break;
    CH >>= 1;
  }
  if (need > ws_size) return;

  float2* tW  = (float2*)(ws + o_tW);
  float2* tH  = (float2*)(ws + o_tH);
  float2* tAB = (float2*)(ws + o_tAB);
  u16* wT1 = (u16*)(ws + o_wT1);
  u16* wT2 = (u16*)(ws + o_wT2);
  float* gp = (float*)(ws + o_gp);
  float* g  = (float*)(ws + o_g);
  float* hb = (float*)(ws + o_h);
  float* rt = (float*)(ws + o_rt);
  float* ps = (float*)(ws + o_ps);
  float* pq = (float*)(ws + o_pq);
  float* bs = (float*)(ws + o_bs);
  float* bh = (float*)(ws + o_bh);
  u16* v   = (u16*)(ws + o_v);
  u32* A1p = (u32*)(ws + o_A1);
  u16* lraw = (u16*)d_out;

  int ntab = NWF*56 + 56*56 + 56*NWF;
  k_tables<<<(ntab+255)/256, 256, 0, stream>>>(tW, tH, tAB);
  k_wt<<<(NDIM*NMED+255)/256, 256, 0, stream>>>(w_pw1, wT1, NDIM, NMED);
  k_wt<<<(NMED*NDIM+255)/256, 256, 0, stream>>>(w_pw2, wT2, NMED, NDIM);

  k_gpart<<<dim3(NH, NB), 384, 0, stream>>>(x, gp);
  k_gfinal<<<NB, 384, 0, stream>>>(gp, g);
  k_rmlp1<<<NB, 128, 0, stream>>>(g, w_r1, r_s, r_b, hb);
  k_rmlp2<<<dim3(NMED/256, NB), 256, 0, stream>>>(hb, w_r2, rt);

  gemm_bt<0, float><<<dim3(NPIX/128, NMED/128), 256, 0, stream>>>(x, wT1, nullptr, v,
      NPIX, NMED, NDIM, a1s, a1b);

  k_dwconv<<<dim3(3, NH, NB), 256, 0, stream>>>(v, dwk, dwb, lraw, ps, pq);
  k_bnstats<<<3, 256, 0, stream>>>(ps, pq, bng, bnb, bs, bh);

  for (int b0 = 0; b0 < NB; b0 += CH){
    size_t pixoff = (size_t)b0*NH*NW*NMED;
    k_fftw_mfma <<<dim3(NMED/128, NH,  CH), 256, 0, stream>>>(v + pixoff, A1p, tW);
    k_ffth_fused<<<dim3(NMED/128, NWF, CH), 256, 0, stream>>>(A1p, tH, rt + (size_t)b0*NFIL*NMED, cw);
    k_ifftw_mfma<<<dim3(NMED/128, NH,  CH), 256, 0, stream>>>(A1p, tAB, lraw + pixoff, bs, bh,
                                                              l_s, l_b, v + pixoff);
  }

  gemm_bt<1, u16><<<dim3(NPIX/128, NDIM/128), 256, 0, stream>>>(v, wT2, out, nullptr,
      NPIX, NDIM, NMED, nullptr, nullptr);
}